// Round 26
// baseline (587.051 us; speedup 1.0000x reference)
//
#include <hip/hip_runtime.h>
#include <cstdint>
#include <cstddef>

#define N_NODES 20000
#define N_EDGES 160000
#define IN_CH   128
#define NH      16
#define CD      32
#define HC      512   // NH*CD
#define ED      93
#define EDP     96    // ED padded to multiple of 32
#define NB      64
#define NCAT    2048  // q|k|v|skip GEMM output cols (all bf16)
#define NSLICE  8
#define DEGSLK  2048  // max-degree slack for node-chunked edge phase
#define NPAIR   10000 // edge-pair blocks (2 nodes per block)

typedef __attribute__((ext_vector_type(8))) short short8;
typedef __attribute__((ext_vector_type(4))) float f32x4;
typedef unsigned short ushort_t;

// ---------------------------------------------------------------- utilities

__device__ inline ushort_t f2bf(float f) {
    unsigned int u = __float_as_uint(f);
    u = (u + 0x7FFF + ((u >> 16) & 1)) >> 16;   // RNE
    return (ushort_t)u;
}
__device__ inline float bf2f(ushort_t u) {
    return __uint_as_float((unsigned)u << 16);
}
__device__ inline void unpack8(uint4 u, float* o) {
    o[0] = bf2f((ushort_t)(u.x & 0xffff)); o[1] = bf2f((ushort_t)(u.x >> 16));
    o[2] = bf2f((ushort_t)(u.y & 0xffff)); o[3] = bf2f((ushort_t)(u.y >> 16));
    o[4] = bf2f((ushort_t)(u.z & 0xffff)); o[5] = bf2f((ushort_t)(u.z >> 16));
    o[6] = bf2f((ushort_t)(u.w & 0xffff)); o[7] = bf2f((ushort_t)(u.w >> 16));
}
__device__ inline uint4 packf8(const float* f) {
    uint4 u;
    u.x = (unsigned)f2bf(f[0]) | ((unsigned)f2bf(f[1]) << 16);
    u.y = (unsigned)f2bf(f[2]) | ((unsigned)f2bf(f[3]) << 16);
    u.z = (unsigned)f2bf(f[4]) | ((unsigned)f2bf(f[5]) << 16);
    u.w = (unsigned)f2bf(f[6]) | ((unsigned)f2bf(f[7]) << 16);
    return u;
}

// async global->LDS, 16B per lane; lds dest = wave-uniform base + lane*16
__device__ inline void gload_lds16(const void* g, void* l) {
    __builtin_amdgcn_global_load_lds(
        (const __attribute__((address_space(1))) void*)g,
        (__attribute__((address_space(3))) void*)l, 16, 0, 0);
}

__global__ void k_zero_i(int* __restrict__ p, int n) {
    int i = blockIdx.x * blockDim.x + threadIdx.x;
    int stride = gridDim.x * blockDim.x;
    for (; i < n; i += stride) p[i] = 0;
}

// x f32 -> bf16, 8 elems/thread vectorized (n % 8 == 0)
__global__ void k_cvt_x(const float* __restrict__ in, ushort_t* __restrict__ out, int n8) {
    int i = blockIdx.x * blockDim.x + threadIdx.x;
    int stride = gridDim.x * blockDim.x;
    for (; i < n8; i += stride) {
        const float4* p = (const float4*)(in + (size_t)i * 8);
        float4 a = p[0], b = p[1];
        float f[8] = {a.x, a.y, a.z, a.w, b.x, b.y, b.z, b.w};
        *(uint4*)(out + (size_t)i * 8) = packf8(f);
    }
}

// edge_attr [E,93] f32 -> PERMUTED [E,96] bf16: out row p = in row perm[p].
__global__ void k_cvt_ea(const float* __restrict__ in, const int* __restrict__ perm,
                         ushort_t* __restrict__ out) {
    int i = blockIdx.x * blockDim.x + threadIdx.x;
    int stride = gridDim.x * blockDim.x;
    int total = N_EDGES * EDP;
    for (; i < total; i += stride) {
        int p = i / EDP, k = i - p * EDP;
        int e = perm[p];
        out[i] = (k < ED) ? f2bf(in[(size_t)e * ED + k]) : (ushort_t)0;
    }
}

// LDS-tiled transposed weight conversion
__global__ __launch_bounds__(256) void k_cvt_wtT(
    const float* __restrict__ W0, const float* __restrict__ W1,
    const float* __restrict__ W2, const float* __restrict__ W3,
    ushort_t* __restrict__ Wt, int K, int N, int Kp) {
    __shared__ float tile[32][33];
    int z = blockIdx.z;
    const float* W = (z == 0) ? W0 : (z == 1) ? W1 : (z == 2) ? W2 : W3;
    ushort_t* out = Wt + (size_t)z * N * Kp;
    int n0 = blockIdx.x << 5;
    int k0 = blockIdx.y << 5;
    int r = threadIdx.x >> 5;   // 0..7
    int c = threadIdx.x & 31;
#pragma unroll
    for (int rr = 0; rr < 4; ++rr) {
        int k = k0 + r + rr * 8;
        tile[r + rr * 8][c] = (k < K) ? W[(size_t)k * N + n0 + c] : 0.f;
    }
    __syncthreads();
#pragma unroll
    for (int rr = 0; rr < 4; ++rr) {
        int n = n0 + r + rr * 8;
        out[(size_t)n * Kp + k0 + c] = f2bf(tile[c][r + rr * 8]);
    }
}

// bcat[2][2048] = (bq|bk|bv|bs) per layer, one dispatch
__global__ void k_bcat2(
    const float* __restrict__ b0q, const float* __restrict__ b0k,
    const float* __restrict__ b0v, const float* __restrict__ b0s,
    const float* __restrict__ b1q, const float* __restrict__ b1k,
    const float* __restrict__ b1v, const float* __restrict__ b1s,
    float* __restrict__ out) {
    int i = blockIdx.x * blockDim.x + threadIdx.x;
    if (i >= 2 * NCAT) return;
    int l = i >> 11, j = i & (NCAT - 1);
    int s = j >> 9, jj = j & 511;
    const float* b = (l == 0)
        ? ((s == 0) ? b0q : (s == 1) ? b0k : (s == 2) ? b0v : b0s)
        : ((s == 0) ? b1q : (s == 1) ? b1k : (s == 2) ? b1v : b1s);
    out[i] = b[jj];
}

// ---------------------------------------------------------------- CSR build

__global__ void k_hist(const int* __restrict__ dst, int* __restrict__ deg) {
    int i = blockIdx.x * blockDim.x + threadIdx.x;
    if (i < N_EDGES) atomicAdd(&deg[dst[i]], 1);
}

__global__ __launch_bounds__(1024) void k_scan(const int* __restrict__ deg,
                                               int* __restrict__ rowptr,
                                               int* __restrict__ cursor) {
    __shared__ int part[1024];
    int t = threadIdx.x;
    int base = t * 20;
    int loc[20];
    int s = 0;
#pragma unroll
    for (int i = 0; i < 20; ++i) {
        int idx = base + i;
        int v = (idx < N_NODES) ? deg[idx] : 0;
        loc[i] = s; s += v;
    }
    part[t] = s;
    __syncthreads();
    for (int off = 1; off < 1024; off <<= 1) {
        int v = (t >= off) ? part[t - off] : 0;
        __syncthreads();
        part[t] += v;
        __syncthreads();
    }
    int pre = (t > 0) ? part[t - 1] : 0;
#pragma unroll
    for (int i = 0; i < 20; ++i) {
        int idx = base + i;
        if (idx < N_NODES) {
            int v = pre + loc[i];
            rowptr[idx] = v;
            cursor[idx] = v;
        }
    }
    if (t == 1023) rowptr[N_NODES] = part[1023];
}

__global__ void k_scatter(const int* __restrict__ src, const int* __restrict__ dst,
                          int* __restrict__ cursor, int* __restrict__ perm,
                          int* __restrict__ psrc) {
    int i = blockIdx.x * blockDim.x + threadIdx.x;
    if (i >= N_EDGES) return;
    int d = dst[i];
    int p = atomicAdd(&cursor[d], 1);
    perm[p] = i;
    psrc[p] = src[i];
}

// ---------------------------------------------------------------- MEGA kernel
// blocks [0,nq): QKVS GEMM; blocks [nq,nq+neg): edge-GEMM chunk0 (pbase=0, ec).

__global__ __launch_bounds__(256) void k_mega(
    const ushort_t* __restrict__ A, const ushort_t* __restrict__ Bt,
    const float* __restrict__ bias, ushort_t* __restrict__ Yb,
    int M, int K, int N, int nq,
    const ushort_t* __restrict__ Ab, const ushort_t* __restrict__ Bte,
    ushort_t* __restrict__ Ybe, int ec, int neg) {
    __shared__ char smem[49152];
    int tid  = threadIdx.x;
    int lane = tid & 63, wave = tid >> 6;
    int l15 = lane & 15, lg = lane >> 4;
    int wm = (wave >> 1) * 64, wn = (wave & 1) * 64;

    if ((int)blockIdx.x < nq) {
        // ---------------- QKVS body ----------------
        char* As = smem;
        char* Bs = smem + 16384;
        int nt = N >> 7;
        int bid = blockIdx.x;
        int wg;
        if ((nq & 7) == 0) { int cpx = nq >> 3; wg = (bid & 7) * cpx + (bid >> 3); }
        else wg = bid;
        int bm = (wg / nt) * 128, bn = (wg % nt) * 128;

        f32x4 acc[4][4] = {};

        int sr = lane >> 3;
        int su = lane & 7;
        int gu = su ^ sr;

        for (int k0 = 0; k0 < K; k0 += 64) {
#pragma unroll
            for (int i = 0; i < 4; ++i) {
                int rloc = wave * 32 + i * 8;
                int row = rloc + sr;
                if (bm + row < M)
                    gload_lds16(A + (size_t)(bm + row) * K + k0 + gu * 8, As + rloc * 128);
                gload_lds16(Bt + (size_t)(bn + row) * K + k0 + gu * 8, Bs + rloc * 128);
            }
            __syncthreads();

#pragma unroll
            for (int ks = 0; ks < 2; ++ks) {
                short8 af[4], bfr[4];
#pragma unroll
                for (int mr = 0; mr < 4; ++mr) {
                    int r = wm + mr * 16 + l15;
                    af[mr] = *(const short8*)(As + r * 128 + (((ks * 4 + lg) ^ (r & 7)) << 4));
                }
#pragma unroll
                for (int nc = 0; nc < 4; ++nc) {
                    int r = wn + nc * 16 + l15;
                    bfr[nc] = *(const short8*)(Bs + r * 128 + (((ks * 4 + lg) ^ (r & 7)) << 4));
                }
#pragma unroll
                for (int mr = 0; mr < 4; ++mr)
#pragma unroll
                    for (int nc = 0; nc < 4; ++nc)
                        acc[mr][nc] = __builtin_amdgcn_mfma_f32_16x16x32_bf16(
                            af[mr], bfr[nc], acc[mr][nc], 0, 0, 0);
            }
            __syncthreads();
        }

        char* Cs = smem;
#pragma unroll
        for (int mr = 0; mr < 4; ++mr) {
#pragma unroll
            for (int nc = 0; nc < 4; ++nc) {
                int coll = wn + nc * 16 + l15;
                float b = bias ? bias[bn + coll] : 0.f;
                int u0 = coll >> 3;
#pragma unroll
                for (int j = 0; j < 4; ++j) {
                    int row = wm + mr * 16 + lg * 4 + j;
                    int u = u0 ^ (row & 7);
                    *(ushort_t*)(Cs + row * 256 + (u << 4) + ((coll & 7) << 1)) =
                        f2bf(acc[mr][nc][j] + b);
                }
            }
        }
        __syncthreads();
        {
            int rsub = tid >> 4;
            int un   = tid & 15;
#pragma unroll
            for (int i = 0; i < 8; ++i) {
                int row = i * 16 + rsub;
                int gr = bm + row;
                if (gr < M) {
                    int u = un ^ (row & 7);
                    *(uint4*)(Yb + (size_t)gr * N + bn + un * 8) =
                        *(const uint4*)(Cs + row * 256 + (u << 4));
                }
            }
        }
    } else {
        // ---------------- edge-GEMM body (chunk 0: pbase = 0) ----------------
        char* As = smem;
        char* Bs = smem + 24576;
        int bid = blockIdx.x - nq;
        int wg;
        if ((neg & 7) == 0) { int cpx = neg >> 3; wg = (bid & 7) * cpx + (bid >> 3); }
        else wg = bid;
        int bm = (wg >> 2) * 128;
        int n0 = (wg & 3) * 128;

        int srow = tid >> 1;
        int h    = tid & 1;
        int ssw  = ((srow >> 1) & 3) << 4;
        {
            int gm = bm + srow;
            uint4 va[6];
#pragma unroll
            for (int i = 0; i < 6; ++i) { va[i].x = va[i].y = va[i].z = va[i].w = 0; }
            if (gm < ec) {
                const uint4* ga = (const uint4*)(Ab + (size_t)gm * EDP + h * 48);
#pragma unroll
                for (int i = 0; i < 6; ++i) va[i] = ga[i];
            }
            char* dsta = As + srow * 192;
#pragma unroll
            for (int i = 0; i < 6; ++i) {
                int c = h * 96 + i * 16;
                *(uint4*)(dsta + ((c & ~63) | ((c & 63) ^ ssw))) = va[i];
            }
            uint4 vb[6];
            {
                const uint4* gb = (const uint4*)(Bte + (size_t)(n0 + srow) * EDP + h * 48);
#pragma unroll
                for (int i = 0; i < 6; ++i) vb[i] = gb[i];
            }
            char* dstb = Bs + srow * 192;
#pragma unroll
            for (int i = 0; i < 6; ++i) {
                int c = h * 96 + i * 16;
                *(uint4*)(dstb + ((c & ~63) | ((c & 63) ^ ssw))) = vb[i];
            }
        }
        __syncthreads();

        int fsw = ((l15 >> 1) & 3) << 4;

        f32x4 acc[4][4] = {};
#pragma unroll
        for (int ks = 0; ks < 3; ++ks) {
            short8 af[4], bfr[4];
#pragma unroll
            for (int mr = 0; mr < 4; ++mr) {
                int r = wm + mr * 16 + l15;
                int c = ks * 64 + ((lg * 16) ^ fsw);
                af[mr] = *(const short8*)(As + r * 192 + c);
            }
#pragma unroll
            for (int nc = 0; nc < 4; ++nc) {
                int r = wn + nc * 16 + l15;
                int c = ks * 64 + ((lg * 16) ^ fsw);
                bfr[nc] = *(const short8*)(Bs + r * 192 + c);
            }
#pragma unroll
            for (int mr = 0; mr < 4; ++mr)
#pragma unroll
                for (int nc = 0; nc < 4; ++nc)
                    acc[mr][nc] = __builtin_amdgcn_mfma_f32_16x16x32_bf16(
                        af[mr], bfr[nc], acc[mr][nc], 0, 0, 0);
        }
        __syncthreads();

        char* Cs = smem;   // 128 rows * 288B stride = 36864
#pragma unroll
        for (int mr = 0; mr < 4; ++mr) {
#pragma unroll
            for (int nc = 0; nc < 4; ++nc) {
                int col = wn + nc * 16 + l15;
#pragma unroll
                for (int j = 0; j < 4; ++j) {
                    int row = wm + mr * 16 + lg * 4 + j;
                    *(ushort_t*)(Cs + row * 288 + col * 2) = f2bf(acc[mr][nc][j]);
                }
            }
        }
        __syncthreads();

        {
            int rsub = tid >> 4;
            int un   = tid & 15;
#pragma unroll
            for (int i = 0; i < 8; ++i) {
                int row = i * 16 + rsub;
                if (bm + row < ec) {
                    *(uint4*)(Ybe + (size_t)(bm + row) * HC + n0 + un * 8) =
                        *(const uint4*)(Cs + row * 288 + un * 16);
                }
            }
        }
    }
}

// ---------------------------------------------------------------- PIPE kernel
// blocks [0,npair): edge phase for 2 nodes/block (chunk window [e0,elim) of ebR);
// blocks [npair,npair+neg2): edge-GEMM for NEXT chunk (pbase2, ec2) -> ebW.

__global__ __launch_bounds__(256) void k_pipe(
    const ushort_t* __restrict__ qkvs, const ushort_t* __restrict__ ebR,
    const int* __restrict__ psrc, const int* __restrict__ rowptr,
    ushort_t* __restrict__ xoutb, int e0, int elim, int npair,
    const ushort_t* __restrict__ Ab, const ushort_t* __restrict__ Bte,
    ushort_t* __restrict__ ebW, int pbase2, int ec2, int neg2) {
    __shared__ char smem[49152];
    int tid  = threadIdx.x;

    if ((int)blockIdx.x < npair) {
        // ---------------- edge phase, 2 nodes per block ----------------
        int half = tid >> 7;          // 0/1: node within pair
        int t    = tid & 127;
        int w    = t >> 6;            // wave within half (waves don't straddle halves)
        int lane = t & 63;
        int c0 = lane * 8;
        int h = lane >> 2;
        int n = blockIdx.x * 2 + half;     // < 20000 always
        int beg = rowptr[n], end = rowptr[n + 1];
        bool act = (beg >= e0 && beg < elim);

        float q[8];
        unpack8(*(const uint4*)(qkvs + (size_t)n * NCAT + c0), q);

        float mm = -1e30f, dd = 0.f, a[8];
#pragma unroll
        for (int j = 0; j < 8; ++j) a[j] = 0.f;

        int iend = act ? end : 0;
        int i = (act ? beg : 0) + w;
        uint4 ku4, vu4, eu4;
        if (i < iend) {
            int sn = psrc[i];
            ku4 = *(const uint4*)(qkvs + (size_t)sn * NCAT + 512 + c0);
            vu4 = *(const uint4*)(qkvs + (size_t)sn * NCAT + 1024 + c0);
            eu4 = *(const uint4*)(ebR + (size_t)(i - e0) * HC + c0);
        }
        while (i < iend) {
            uint4 kc = ku4, vc = vu4, ec = eu4;
            int inext = i + 2;
            if (inext < iend) {
                int sn2 = psrc[inext];
                ku4 = *(const uint4*)(qkvs + (size_t)sn2 * NCAT + 512 + c0);
                vu4 = *(const uint4*)(qkvs + (size_t)sn2 * NCAT + 1024 + c0);
                eu4 = *(const uint4*)(ebR + (size_t)(inext - e0) * HC + c0);
            }
            float kk[8], vv[8], ee[8];
            unpack8(kc, kk); unpack8(vc, vv); unpack8(ec, ee);
            float part = 0.f;
#pragma unroll
            for (int j = 0; j < 8; ++j) part += q[j] * (kk[j] + ee[j]);
            part += __shfl_xor(part, 1);
            part += __shfl_xor(part, 2);
            float s = part * 0.17677669529663687f;   // /sqrt(32)
            float mn = fmaxf(mm, s);
            float sc = __expf(mm - mn);
            float p  = __expf(s - mn);
            dd = dd * sc + p;
            mm = mn;
#pragma unroll
            for (int j = 0; j < 8; ++j) a[j] = a[j] * sc + p * (vv[j] + ee[j]);
            i = inext;
        }

        // merge the two wave states of this half, finish, store bf16
        float* sm_acc = (float*)smem + (size_t)half * 512;            // [2][512]
        float* sm_m   = (float*)(smem + 4096) + half * 16;            // [2][16]
        float* sm_d   = (float*)(smem + 4096 + 128) + half * 16;      // [2][16]
        if (w == 1) {
#pragma unroll
            for (int j = 0; j < 8; ++j) sm_acc[c0 + j] = a[j];
            if ((lane & 3) == 0) { sm_m[h] = mm; sm_d[h] = dd; }
        }
        __syncthreads();
        if (w == 0 && act) {
            float m1 = sm_m[h], d1 = sm_d[h];
            float M = fmaxf(mm, m1);
            float sc0 = __expf(mm - M);
            float sc1 = __expf(m1 - M);
            dd = dd * sc0 + d1 * sc1;
            float inv = (dd > 0.f) ? 1.f / dd : 0.f;
            float sk[8];
            unpack8(*(const uint4*)(qkvs + (size_t)n * NCAT + 1536 + c0), sk);
            float o[8];
#pragma unroll
            for (int j = 0; j < 8; ++j) {
                float msg = (a[j] * sc0 + sm_acc[c0 + j] * sc1) * inv;
                float v = msg + sk[j];
                o[j] = v >= 0.f ? v : 0.2f * v;
            }
            *(uint4*)(xoutb + (size_t)n * HC + c0) = packf8(o);
        }
    } else {
        // ---------------- edge-GEMM body (next chunk) ----------------
        int lane = tid & 63, wave = tid >> 6;
        int l15 = lane & 15, lg = lane >> 4;
        int wm = (wave >> 1) * 64, wn = (wave & 1) * 64;
        char* As = smem;
        char* Bs = smem + 24576;
        int bid = blockIdx.x - npair;
        int wg;
        if ((neg2 & 7) == 0) { int cpx = neg2 >> 3; wg = (bid & 7) * cpx + (bid >> 3); }
        else wg = bid;
        int bm = (wg >> 2) * 128;
        int n0 = (wg & 3) * 128;

        int srow = tid >> 1;
        int h    = tid & 1;
        int ssw  = ((srow >> 1) & 3) << 4;
        {
            int gm = bm + srow;
            uint4 va[6];
#pragma unroll
            for (int i = 0; i < 6; ++i) { va[i].x = va[i].y = va[i].z = va[i].w = 0; }
            if (gm < ec2) {
                const uint4* ga = (const uint4*)(Ab + (size_t)(pbase2 + gm) * EDP + h * 48);
#pragma unroll
                for (int i = 0; i < 6; ++i) va[i] = ga[i];
            }
            char* dsta = As + srow * 192;
#pragma unroll
            for (int i = 0; i < 6; ++i) {
                int c = h * 96 + i * 16;
                *(uint4*)(dsta + ((c & ~63) | ((c & 63) ^ ssw))) = va[i];
            }
            uint4 vb[6];
            {
                const uint4* gb = (const uint4*)(Bte + (size_t)(n0 + srow) * EDP + h * 48);
#pragma unroll
                for (int i = 0; i < 6; ++i) vb[i] = gb[i];
            }
            char* dstb = Bs + srow * 192;
#pragma unroll
            for (int i = 0; i < 6; ++i) {
                int c = h * 96 + i * 16;
                *(uint4*)(dstb + ((c & ~63) | ((c & 63) ^ ssw))) = vb[i];
            }
        }
        __syncthreads();

        int fsw = ((l15 >> 1) & 3) << 4;

        f32x4 acc[4][4] = {};
#pragma unroll
        for (int ks = 0; ks < 3; ++ks) {
            short8 af[4], bfr[4];
#pragma unroll
            for (int mr = 0; mr < 4; ++mr) {
                int r = wm + mr * 16 + l15;
                int c = ks * 64 + ((lg * 16) ^ fsw);
                af[mr] = *(const short8*)(As + r * 192 + c);
            }
#pragma unroll
            for (int nc = 0; nc < 4; ++nc) {
                int r = wn + nc * 16 + l15;
                int c = ks * 64 + ((lg * 16) ^ fsw);
                bfr[nc] = *(const short8*)(Bs + r * 192 + c);
            }
#pragma unroll
            for (int mr = 0; mr < 4; ++mr)
#pragma unroll
                for (int nc = 0; nc < 4; ++nc)
                    acc[mr][nc] = __builtin_amdgcn_mfma_f32_16x16x32_bf16(
                        af[mr], bfr[nc], acc[mr][nc], 0, 0, 0);
        }
        __syncthreads();

        char* Cs = smem;   // 128 rows * 288B stride = 36864
#pragma unroll
        for (int mr = 0; mr < 4; ++mr) {
#pragma unroll
            for (int nc = 0; nc < 4; ++nc) {
                int col = wn + nc * 16 + l15;
#pragma unroll
                for (int j = 0; j < 4; ++j) {
                    int row = wm + mr * 16 + lg * 4 + j;
                    *(ushort_t*)(Cs + row * 288 + col * 2) = f2bf(acc[mr][nc][j]);
                }
            }
        }
        __syncthreads();

        {
            int rsub = tid >> 4;
            int un   = tid & 15;
#pragma unroll
            for (int i = 0; i < 8; ++i) {
                int row = i * 16 + rsub;
                if (bm + row < ec2) {
                    *(uint4*)(ebW + (size_t)(bm + row) * HC + n0 + un * 8) =
                        *(const uint4*)(Cs + row * 288 + un * 16);
                }
            }
        }
    }
}

// ---------------------------------------------------------------- pooling (bf16 in)

__global__ __launch_bounds__(256) void k_pool2(
    const ushort_t* __restrict__ xb, const int* __restrict__ batch,
    float* __restrict__ psum_p, float* __restrict__ pmax_p, int* __restrict__ cnt) {
    int b = blockIdx.x;
    int s = blockIdx.y;
    int lo = 0, hi = N_NODES;
    while (lo < hi) { int mid = (lo + hi) >> 1; if (batch[mid] < b) lo = mid + 1; else hi = mid; }
    int beg = lo;
    hi = N_NODES;
    while (lo < hi) { int mid = (lo + hi) >> 1; if (batch[mid] < b + 1) lo = mid + 1; else hi = mid; }
    int end = lo;
    if (s == 0 && threadIdx.x == 0) cnt[b] = end - beg;
    int cn = end - beg;
    int per = (cn + NSLICE - 1) / NSLICE;
    int nb = beg + s * per;
    int ne = nb + per; if (ne > end) ne = end;
    int c0 = threadIdx.x * 2;
    float s0 = 0.f, s1 = 0.f, m0 = -1e30f, m1 = -1e30f;
    for (int n = nb; n < ne; ++n) {
        unsigned int v = *(const unsigned int*)(xb + (size_t)n * HC + c0);
        float v0 = bf2f((ushort_t)(v & 0xffff));
        float v1 = bf2f((ushort_t)(v >> 16));
        s0 += v0; s1 += v1;
        m0 = fmaxf(m0, v0); m1 = fmaxf(m1, v1);
    }
    size_t o = ((size_t)s * NB + b) * HC + c0;
    psum_p[o] = s0; psum_p[o + 1] = s1;
    pmax_p[o] = m0; pmax_p[o + 1] = m1;
}

__global__ void k_poolfin(const float* __restrict__ psum_p, const float* __restrict__ pmax_p,
                          const int* __restrict__ cnt, float* __restrict__ hsum, int mode) {
    int i = blockIdx.x * blockDim.x + threadIdx.x;
    if (i >= NB * 1024) return;
    int b = i >> 10, c = i & 1023;
    float val;
    if (c < HC) {
        float s = 0.f;
#pragma unroll
        for (int sl = 0; sl < NSLICE; ++sl)
            s += psum_p[((size_t)sl * NB + b) * HC + c];
        int ct = cnt[b];
        val = s / (float)(ct > 0 ? ct : 1);
    } else {
        int cc = c - HC;
        float m = -1e30f;
#pragma unroll
        for (int sl = 0; sl < NSLICE; ++sl)
            m = fmaxf(m, pmax_p[((size_t)sl * NB + b) * HC + cc]);
        val = m;
    }
    if (mode == 0) hsum[i] = val;
    else hsum[i] += val;
}

// ---------------------------------------------------------------- MLP head

__global__ __launch_bounds__(256) void k_head(
    const float* __restrict__ hsum, const float* __restrict__ fc1W,
    const float* __restrict__ fc1b, const float* __restrict__ fc2W,
    const float* __restrict__ fc2b, float* __restrict__ out) {
    int b = blockIdx.x;
    int j = threadIdx.x;
    __shared__ float hs[256];
    float acc = fc1b[j];
    const float* hin = hsum + (size_t)b * 1024;
    for (int k = 0; k < 1024; ++k) {
        acc += hin[k] * fc1W[(size_t)k * 256 + j];
    }
    hs[j] = fmaxf(acc, 0.f);
    __syncthreads();
    if (j < 32) {
        float o = fc2b[j];
        for (int k = 0; k < 256; ++k) o += hs[k] * fc2W[(size_t)k * 32 + j];
        out[b * 32 + j] = o;
    }
}

// ---------------------------------------------------------------- driver

extern "C" void kernel_launch(void* const* d_in, const int* in_sizes, int n_in,
                              void* d_out, int out_size, void* d_ws, size_t ws_size,
                              hipStream_t stream) {
    const float* x      = (const float*)d_in[0];
    const float* ea     = (const float*)d_in[1];
    const int*   ei     = (const int*)d_in[2];
    const int*   batch  = (const int*)d_in[3];
    const int* src = ei;
    const int* dst = ei + N_EDGES;

    const float* t1_Wq = (const float*)d_in[4];
    const float* t1_bq = (const float*)d_in[5];
    const float* t1_Wk = (const float*)d_in[6];
    const float* t1_bk = (const float*)d_in[7];
    const float* t1_Wv = (const float*)d_in[8];
    const float* t1_bv = (const float*)d_in[9];
    const float* t1_We = (const float*)d_in[10];
    const float* t1_Ws = (const float*)d_in[11];
    const float* t1_bs = (const float*)d_in[12];
    const float* t2_Wq = (const float*)d_in[13];
    const float* t2_bq = (const float*)d_in[14];
    const float* t2_Wk = (const float*)d_in[15];
    const float* t2_bk = (const float*)d_in[16];
    const float* t2_Wv = (const float*)d_in[17];
    const float* t2_bv = (const float*)d_in[18];
    const float* t2_We = (const float*)d_in[19];
    const float* t2_Ws = (const float*)d_in[20];
    const float* t2_bs = (const float*)d_in[21];
    const float* fc1_W = (const float*)d_in[22];
    const float* fc1_b = (const float*)d_in[23];
    const float* fc2_W = (const float*)d_in[24];
    const float* fc2_b = (const float*)d_in[25];

    char* ws = (char*)d_ws;
    size_t off = 0;
    auto alloc = [&](size_t bytes) -> void* {
        void* p = ws + off;
        off = (off + bytes + 255) & ~(size_t)255;
        return p;
    };

    // ---- fixed buffers ----
    ushort_t* qkvs = (ushort_t*)alloc((size_t)N_NODES * NCAT * 2);  // q|k|v|skip bf16
    float* psum_p = (float*)alloc((size_t)NSLICE * NB * HC * 4);
    float* pmax_p = (float*)alloc((size_t)NSLICE * NB * HC * 4);
    float* hsum = (float*)alloc((size_t)NB * 1024 * 4);
    int*   cnt  = (int*)alloc((size_t)NB * 4);
    int* deg    = (int*)alloc((size_t)N_NODES * 4);
    int* rowptr = (int*)alloc((size_t)(N_NODES + 1) * 4);
    int* cursor = (int*)alloc((size_t)N_NODES * 4);
    int* perm   = (int*)alloc((size_t)N_EDGES * 4);
    int* psrc   = (int*)alloc((size_t)N_EDGES * 4);
    ushort_t* x_b  = (ushort_t*)alloc((size_t)N_NODES * IN_CH * 2);
    ushort_t* x1_b = (ushort_t*)alloc((size_t)N_NODES * HC * 2);
    ushort_t* ea_b = (ushort_t*)alloc((size_t)N_EDGES * EDP * 2);   // dst-sorted
    ushort_t* wcat1 = (ushort_t*)alloc((size_t)NCAT * IN_CH * 2);
    ushort_t* wcat2 = (ushort_t*)alloc((size_t)NCAT * HC * 2);
    ushort_t* w_e   = (ushort_t*)alloc((size_t)2 * HC * EDP * 2);  // [2][HC][EDP]
    float* bcat = (float*)alloc((size_t)2 * NCAT * 4);             // [2][NCAT]

    // ---- edge-chunk buffers (double-buffered when chunked) ----
    size_t remain = (ws_size > off) ? (ws_size - off) : 0;
    size_t per_edge = (size_t)HC * 2;                // 1 KiB per edge row
    long cap_rows = (long)(remain / per_edge);
    int nch = -1;
    if (cap_rows >= (long)N_EDGES) nch = 1;
    else {
        for (int c = 2; c <= 64; ++c) {
            long s = (N_EDGES + c - 1) / c;
            if (2 * (s + DEGSLK) <= cap_rows) { nch = c; break; }
        }
        if (nch < 0) nch = 64;
    }
    int S = (N_EDGES + nch - 1) / nch;
    size_t bufrows = (nch == 1) ? (size_t)N_EDGES : (size_t)(S + DEGSLK);
    ushort_t* ebA = (ushort_t*)(ws + off);
    ushort_t* ebB = (nch == 1) ? ebA : ebA + bufrows * HC;
    (void)in_sizes; (void)n_in; (void)out_size;

    // ---- CSR build (before ea conversion: k_cvt_ea uses perm)
    hipLaunchKernelGGL(k_zero_i, dim3(79), dim3(256), 0, stream, deg, N_NODES);
    hipLaunchKernelGGL(k_hist, dim3((N_EDGES + 255) / 256), dim3(256), 0, stream, dst, deg);
    hipLaunchKernelGGL(k_scan, dim3(1), dim3(1024), 0, stream, deg, rowptr, cursor);
    hipLaunchKernelGGL(k_scatter, dim3((N_EDGES + 255) / 256), dim3(256), 0, stream,
                       src, dst, cursor, perm, psrc);

    // ---- conversions
    hipLaunchKernelGGL(k_cvt_x, dim3(512), dim3(256), 0, stream, x, x_b,
                       N_NODES * IN_CH / 8);
    hipLaunchKernelGGL(k_cvt_ea, dim3(4096), dim3(256), 0, stream, ea, perm, ea_b);
    hipLaunchKernelGGL(k_cvt_wtT, dim3(HC / 32, IN_CH / 32, 4), dim3(256), 0, stream,
                       t1_Wq, t1_Wk, t1_Wv, t1_Ws, wcat1, IN_CH, HC, IN_CH);
    hipLaunchKernelGGL(k_cvt_wtT, dim3(HC / 32, HC / 32, 4), dim3(256), 0, stream,
                       t2_Wq, t2_Wk, t2_Wv, t2_Ws, wcat2, HC, HC, HC);
    hipLaunchKernelGGL(k_cvt_wtT, dim3(HC / 32, EDP / 32, 2), dim3(256), 0, stream,
                       t1_We, t2_We, t1_We, t1_We, w_e, ED, HC, EDP);
    hipLaunchKernelGGL(k_bcat2, dim3(16), dim3(256), 0, stream,
                       t1_bq, t1_bk, t1_bv, t1_bs, t2_bq, t2_bk, t2_bv, t2_bs, bcat);

    auto run_layer = [&](const ushort_t* xin_b, int Kin, const ushort_t* wcat,
                         const float* bc, const ushort_t* we,
                         ushort_t* xoutb, int poolmode) {
        int mt = (N_NODES + 127) / 128;
        int nt = NCAT / 128;
        int nq = mt * nt;                            // 2512

        // chunk 0 fused with QKVS
        int ec0 = (nch == 1) ? N_EDGES
                             : (int)((S + DEGSLK < N_EDGES) ? (S + DEGSLK) : N_EDGES);
        int neg0 = ((ec0 + 127) / 128) * 4;
        hipLaunchKernelGGL(k_mega, dim3(nq + neg0), dim3(256), 0, stream,
                           xin_b, wcat, bc, qkvs, N_NODES, Kin, NCAT, nq,
                           ea_b, we, ebA, ec0, neg0);

        // pipeline: edge_fc(ci) fused with egemm(ci+1)
        for (int ci = 0; ci < nch; ++ci) {
            int e0 = ci * S;
            if (e0 >= N_EDGES) break;
            ushort_t* ebR = ((ci & 1) == 0) ? ebA : ebB;
            int elim = (ci == nch - 1) ? (N_EDGES + 1) : (e0 + S);
            int cj = ci + 1;
            int neg2 = 0, pb2 = 0, ec2 = 0;
            ushort_t* ebW = ebA;
            if (cj < nch && cj * S < N_EDGES) {
                pb2 = cj * S;
                long ecl = (long)S + DEGSLK;
                if (ecl > N_EDGES - pb2) ecl = N_EDGES - pb2;
                ec2 = (int)ecl;
                neg2 = ((ec2 + 127) / 128) * 4;
                ebW = ((cj & 1) == 0) ? ebA : ebB;
            }
            hipLaunchKernelGGL(k_pipe, dim3(NPAIR + neg2), dim3(256), 0, stream,
                               qkvs, ebR, psrc, rowptr, xoutb, e0, elim, NPAIR,
                               ea_b, we, ebW, pb2, ec2, neg2);
        }

        // pooling (bf16 input, atomic-free partials)
        hipLaunchKernelGGL(k_pool2, dim3(NB, NSLICE), dim3(256), 0, stream,
                           xoutb, batch, psum_p, pmax_p, cnt);
        hipLaunchKernelGGL(k_poolfin, dim3((NB * 1024 + 255) / 256), dim3(256), 0, stream,
                           psum_p, pmax_p, cnt, hsum, poolmode);
    };

    // layer 1: x_b (N,128) -> x1_b ; layer 2: x1_b (N,512) -> x1_b
    run_layer(x_b, IN_CH, wcat1, bcat, w_e, x1_b, /*poolmode=*/0);
    run_layer(x1_b, HC, wcat2, bcat + NCAT, w_e + (size_t)HC * EDP, x1_b, /*poolmode=*/1);

    hipLaunchKernelGGL(k_head, dim3(NB), dim3(256), 0, stream,
                       hsum, fc1_W, fc1_b, fc2_W, fc2_b, (float*)d_out);
}

// Round 27
// 577.399 us; speedup vs baseline: 1.0167x; 1.0167x over previous
//
#include <hip/hip_runtime.h>
#include <cstdint>
#include <cstddef>

#define N_NODES 20000
#define N_EDGES 160000
#define IN_CH   128
#define NH      16
#define CD      32
#define HC      512   // NH*CD
#define ED      93
#define EDP     96    // ea_b row stride (bf16)
#define KEP     128   // padded K for edge GEMM (We zero-padded)
#define NB      64
#define NCAT    2048  // q|k|v|skip GEMM output cols (all bf16)
#define NSLICE  8
#define DEGSLK  2048  // max-degree slack for node-chunked edge phase

typedef __attribute__((ext_vector_type(8))) short short8;
typedef __attribute__((ext_vector_type(4))) float f32x4;
typedef unsigned short ushort_t;

// ---------------------------------------------------------------- utilities

__device__ inline ushort_t f2bf(float f) {
    unsigned int u = __float_as_uint(f);
    u = (u + 0x7FFF + ((u >> 16) & 1)) >> 16;   // RNE
    return (ushort_t)u;
}
__device__ inline float bf2f(ushort_t u) {
    return __uint_as_float((unsigned)u << 16);
}
__device__ inline void unpack8(uint4 u, float* o) {
    o[0] = bf2f((ushort_t)(u.x & 0xffff)); o[1] = bf2f((ushort_t)(u.x >> 16));
    o[2] = bf2f((ushort_t)(u.y & 0xffff)); o[3] = bf2f((ushort_t)(u.y >> 16));
    o[4] = bf2f((ushort_t)(u.z & 0xffff)); o[5] = bf2f((ushort_t)(u.z >> 16));
    o[6] = bf2f((ushort_t)(u.w & 0xffff)); o[7] = bf2f((ushort_t)(u.w >> 16));
}
__device__ inline uint4 packf8(const float* f) {
    uint4 u;
    u.x = (unsigned)f2bf(f[0]) | ((unsigned)f2bf(f[1]) << 16);
    u.y = (unsigned)f2bf(f[2]) | ((unsigned)f2bf(f[3]) << 16);
    u.z = (unsigned)f2bf(f[4]) | ((unsigned)f2bf(f[5]) << 16);
    u.w = (unsigned)f2bf(f[6]) | ((unsigned)f2bf(f[7]) << 16);
    return u;
}

// async global->LDS, 16B per lane; lds dest = wave-uniform base + lane*16
__device__ inline void gload_lds16(const void* g, void* l) {
    __builtin_amdgcn_global_load_lds(
        (const __attribute__((address_space(1))) void*)g,
        (__attribute__((address_space(3))) void*)l, 16, 0, 0);
}

__global__ void k_zero_i(int* __restrict__ p, int n) {
    int i = blockIdx.x * blockDim.x + threadIdx.x;
    int stride = gridDim.x * blockDim.x;
    for (; i < n; i += stride) p[i] = 0;
}

// x f32 -> bf16, 8 elems/thread vectorized (n % 8 == 0)
__global__ void k_cvt_x(const float* __restrict__ in, ushort_t* __restrict__ out, int n8) {
    int i = blockIdx.x * blockDim.x + threadIdx.x;
    int stride = gridDim.x * blockDim.x;
    for (; i < n8; i += stride) {
        const float4* p = (const float4*)(in + (size_t)i * 8);
        float4 a = p[0], b = p[1];
        float f[8] = {a.x, a.y, a.z, a.w, b.x, b.y, b.z, b.w};
        *(uint4*)(out + (size_t)i * 8) = packf8(f);
    }
}

// edge_attr [E,93] f32 -> PERMUTED [E,96] bf16: out row p = in row perm[p].
__global__ void k_cvt_ea(const float* __restrict__ in, const int* __restrict__ perm,
                         ushort_t* __restrict__ out) {
    int i = blockIdx.x * blockDim.x + threadIdx.x;
    int stride = gridDim.x * blockDim.x;
    int total = N_EDGES * EDP;
    for (; i < total; i += stride) {
        int p = i / EDP, k = i - p * EDP;
        int e = perm[p];
        out[i] = (k < ED) ? f2bf(in[(size_t)e * ED + k]) : (ushort_t)0;
    }
}

// LDS-tiled transposed weight conversion
__global__ __launch_bounds__(256) void k_cvt_wtT(
    const float* __restrict__ W0, const float* __restrict__ W1,
    const float* __restrict__ W2, const float* __restrict__ W3,
    ushort_t* __restrict__ Wt, int K, int N, int Kp) {
    __shared__ float tile[32][33];
    int z = blockIdx.z;
    const float* W = (z == 0) ? W0 : (z == 1) ? W1 : (z == 2) ? W2 : W3;
    ushort_t* out = Wt + (size_t)z * N * Kp;
    int n0 = blockIdx.x << 5;
    int k0 = blockIdx.y << 5;
    int r = threadIdx.x >> 5;   // 0..7
    int c = threadIdx.x & 31;
#pragma unroll
    for (int rr = 0; rr < 4; ++rr) {
        int k = k0 + r + rr * 8;
        tile[r + rr * 8][c] = (k < K) ? W[(size_t)k * N + n0 + c] : 0.f;
    }
    __syncthreads();
#pragma unroll
    for (int rr = 0; rr < 4; ++rr) {
        int n = n0 + r + rr * 8;
        out[(size_t)n * Kp + k0 + c] = f2bf(tile[c][r + rr * 8]);
    }
}

// bcat[2][2048] = (bq|bk|bv|bs) per layer, one dispatch
__global__ void k_bcat2(
    const float* __restrict__ b0q, const float* __restrict__ b0k,
    const float* __restrict__ b0v, const float* __restrict__ b0s,
    const float* __restrict__ b1q, const float* __restrict__ b1k,
    const float* __restrict__ b1v, const float* __restrict__ b1s,
    float* __restrict__ out) {
    int i = blockIdx.x * blockDim.x + threadIdx.x;
    if (i >= 2 * NCAT) return;
    int l = i >> 11, j = i & (NCAT - 1);
    int s = j >> 9, jj = j & 511;
    const float* b = (l == 0)
        ? ((s == 0) ? b0q : (s == 1) ? b0k : (s == 2) ? b0v : b0s)
        : ((s == 0) ? b1q : (s == 1) ? b1k : (s == 2) ? b1v : b1s);
    out[i] = b[jj];
}

// ---------------------------------------------------------------- CSR build

__global__ void k_hist(const int* __restrict__ dst, int* __restrict__ deg) {
    int i = blockIdx.x * blockDim.x + threadIdx.x;
    if (i < N_EDGES) atomicAdd(&deg[dst[i]], 1);
}

__global__ __launch_bounds__(1024) void k_scan(const int* __restrict__ deg,
                                               int* __restrict__ rowptr,
                                               int* __restrict__ cursor) {
    __shared__ int part[1024];
    int t = threadIdx.x;
    int base = t * 20;
    int loc[20];
    int s = 0;
#pragma unroll
    for (int i = 0; i < 20; ++i) {
        int idx = base + i;
        int v = (idx < N_NODES) ? deg[idx] : 0;
        loc[i] = s; s += v;
    }
    part[t] = s;
    __syncthreads();
    for (int off = 1; off < 1024; off <<= 1) {
        int v = (t >= off) ? part[t - off] : 0;
        __syncthreads();
        part[t] += v;
        __syncthreads();
    }
    int pre = (t > 0) ? part[t - 1] : 0;
#pragma unroll
    for (int i = 0; i < 20; ++i) {
        int idx = base + i;
        if (idx < N_NODES) {
            int v = pre + loc[i];
            rowptr[idx] = v;
            cursor[idx] = v;
        }
    }
    if (t == 1023) rowptr[N_NODES] = part[1023];
}

__global__ void k_scatter(const int* __restrict__ src, const int* __restrict__ dst,
                          int* __restrict__ cursor, int* __restrict__ perm,
                          int* __restrict__ psrc) {
    int i = blockIdx.x * blockDim.x + threadIdx.x;
    if (i >= N_EDGES) return;
    int d = dst[i];
    int p = atomicAdd(&cursor[d], 1);
    perm[p] = i;
    psrc[p] = src[i];
}

// ---------------------------------------------------------------- MEGA kernel
// One unified 128x128 BK=64 MFMA GEMM body, two block ranges:
//   [0,nq):       QKVS  Yb = A[M,K] @ Bt[N,K]^T + bias   (lda=ldb=K)
//   [nq,nq+neg):  edge  Ybe = Ab[ec,96] @ Bte[512,128]^T (lda=96, ldb=128, Kl=128)
// Edge K in [96,128) reads garbage A cols; Bte cols are exact zeros there -> 0.

__global__ __launch_bounds__(256) void k_mega(
    const ushort_t* __restrict__ A, const ushort_t* __restrict__ Bt,
    const float* __restrict__ bias, ushort_t* __restrict__ Yb,
    int M, int K, int N, int nq,
    const ushort_t* __restrict__ Ab, const ushort_t* __restrict__ Bte,
    ushort_t* __restrict__ Ybe, int ec, int neg) {
    __shared__ char smem[32768];
    char* As = smem;
    char* Bs = smem + 16384;

    int tid  = threadIdx.x;
    int lane = tid & 63, wave = tid >> 6;
    int l15 = lane & 15, lg = lane >> 4;
    int wm = (wave >> 1) * 64, wn = (wave & 1) * 64;

    const ushort_t* Ap; const ushort_t* Bp; const float* bp; ushort_t* Yp;
    int Mv, Kl, Nv, lda, ldb, bid, nwg;
    if ((int)blockIdx.x < nq) {
        Ap = A; Bp = Bt; bp = bias; Yp = Yb;
        Mv = M; Kl = K; Nv = N; lda = K; ldb = K;
        bid = blockIdx.x; nwg = nq;
    } else {
        Ap = Ab; Bp = Bte; bp = nullptr; Yp = Ybe;
        Mv = ec; Kl = KEP; Nv = HC; lda = EDP; ldb = KEP;
        bid = blockIdx.x - nq; nwg = neg;
    }
    int wg;
    if ((nwg & 7) == 0) { int cpx = nwg >> 3; wg = (bid & 7) * cpx + (bid >> 3); }
    else wg = bid;
    int nt = Nv >> 7;
    int bm = (wg / nt) * 128, bn = (wg % nt) * 128;

    f32x4 acc[4][4] = {};

    int sr = lane >> 3;
    int su = lane & 7;
    int gu = su ^ sr;

    for (int k0 = 0; k0 < Kl; k0 += 64) {
#pragma unroll
        for (int i = 0; i < 4; ++i) {
            int rloc = wave * 32 + i * 8;
            int row = rloc + sr;
            if (bm + row < Mv)
                gload_lds16(Ap + (size_t)(bm + row) * lda + k0 + gu * 8, As + rloc * 128);
            gload_lds16(Bp + (size_t)(bn + row) * ldb + k0 + gu * 8, Bs + rloc * 128);
        }
        __syncthreads();

#pragma unroll
        for (int ks = 0; ks < 2; ++ks) {
            short8 af[4], bfr[4];
#pragma unroll
            for (int mr = 0; mr < 4; ++mr) {
                int r = wm + mr * 16 + l15;
                af[mr] = *(const short8*)(As + r * 128 + (((ks * 4 + lg) ^ (r & 7)) << 4));
            }
#pragma unroll
            for (int nc = 0; nc < 4; ++nc) {
                int r = wn + nc * 16 + l15;
                bfr[nc] = *(const short8*)(Bs + r * 128 + (((ks * 4 + lg) ^ (r & 7)) << 4));
            }
#pragma unroll
            for (int mr = 0; mr < 4; ++mr)
#pragma unroll
                for (int nc = 0; nc < 4; ++nc)
                    acc[mr][nc] = __builtin_amdgcn_mfma_f32_16x16x32_bf16(
                        af[mr], bfr[nc], acc[mr][nc], 0, 0, 0);
        }
        __syncthreads();
    }

    char* Cs = smem;
#pragma unroll
    for (int mr = 0; mr < 4; ++mr) {
#pragma unroll
        for (int nc = 0; nc < 4; ++nc) {
            int coll = wn + nc * 16 + l15;
            float b = bp ? bp[bn + coll] : 0.f;
            int u0 = coll >> 3;
#pragma unroll
            for (int j = 0; j < 4; ++j) {
                int row = wm + mr * 16 + lg * 4 + j;
                int u = u0 ^ (row & 7);
                *(ushort_t*)(Cs + row * 256 + (u << 4) + ((coll & 7) << 1)) =
                    f2bf(acc[mr][nc][j] + b);
            }
        }
    }
    __syncthreads();
    {
        int rsub = tid >> 4;
        int un   = tid & 15;
#pragma unroll
        for (int i = 0; i < 8; ++i) {
            int row = i * 16 + rsub;
            int gr = bm + row;
            if (gr < Mv) {
                int u = un ^ (row & 7);
                *(uint4*)(Yp + (size_t)gr * Nv + bn + un * 8) =
                    *(const uint4*)(Cs + row * 256 + (u << 4));
            }
        }
    }
}

// ---------------------------------------------------------------- generic GEMM
// Same body, standalone (chunks >= 1 of the edge GEMM). lda/ldb explicit.

__global__ __launch_bounds__(256) void k_mfma_gemm(
    const ushort_t* __restrict__ A, int lda,
    const ushort_t* __restrict__ Bt, int ldb,
    const float* __restrict__ bias, ushort_t* __restrict__ Yb,
    int M, int Kl, int N) {
    __shared__ char smem[32768];
    char* As = smem;
    char* Bs = smem + 16384;

    int tid  = threadIdx.x;
    int lane = tid & 63, wave = tid >> 6;
    int l15 = lane & 15, lg = lane >> 4;
    int nt = N >> 7;
    int nwg = gridDim.x;
    int bid = blockIdx.x;
    int wg;
    if ((nwg & 7) == 0) { int cpx = nwg >> 3; wg = (bid & 7) * cpx + (bid >> 3); }
    else wg = bid;
    int bm = (wg / nt) * 128, bn = (wg % nt) * 128;
    int wm = (wave >> 1) * 64, wn = (wave & 1) * 64;

    f32x4 acc[4][4] = {};

    int sr = lane >> 3;
    int su = lane & 7;
    int gu = su ^ sr;

    for (int k0 = 0; k0 < Kl; k0 += 64) {
#pragma unroll
        for (int i = 0; i < 4; ++i) {
            int rloc = wave * 32 + i * 8;
            int row = rloc + sr;
            if (bm + row < M)
                gload_lds16(A + (size_t)(bm + row) * lda + k0 + gu * 8, As + rloc * 128);
            gload_lds16(Bt + (size_t)(bn + row) * ldb + k0 + gu * 8, Bs + rloc * 128);
        }
        __syncthreads();

#pragma unroll
        for (int ks = 0; ks < 2; ++ks) {
            short8 af[4], bfr[4];
#pragma unroll
            for (int mr = 0; mr < 4; ++mr) {
                int r = wm + mr * 16 + l15;
                af[mr] = *(const short8*)(As + r * 128 + (((ks * 4 + lg) ^ (r & 7)) << 4));
            }
#pragma unroll
            for (int nc = 0; nc < 4; ++nc) {
                int r = wn + nc * 16 + l15;
                bfr[nc] = *(const short8*)(Bs + r * 128 + (((ks * 4 + lg) ^ (r & 7)) << 4));
            }
#pragma unroll
            for (int mr = 0; mr < 4; ++mr)
#pragma unroll
                for (int nc = 0; nc < 4; ++nc)
                    acc[mr][nc] = __builtin_amdgcn_mfma_f32_16x16x32_bf16(
                        af[mr], bfr[nc], acc[mr][nc], 0, 0, 0);
        }
        __syncthreads();
    }

    char* Cs = smem;
#pragma unroll
    for (int mr = 0; mr < 4; ++mr) {
#pragma unroll
        for (int nc = 0; nc < 4; ++nc) {
            int coll = wn + nc * 16 + l15;
            float b = bias ? bias[bn + coll] : 0.f;
            int u0 = coll >> 3;
#pragma unroll
            for (int j = 0; j < 4; ++j) {
                int row = wm + mr * 16 + lg * 4 + j;
                int u = u0 ^ (row & 7);
                *(ushort_t*)(Cs + row * 256 + (u << 4) + ((coll & 7) << 1)) =
                    f2bf(acc[mr][nc][j] + b);
            }
        }
    }
    __syncthreads();
    {
        int rsub = tid >> 4;
        int un   = tid & 15;
#pragma unroll
        for (int i = 0; i < 8; ++i) {
            int row = i * 16 + rsub;
            int gr = bm + row;
            if (gr < M) {
                int u = un ^ (row & 7);
                *(uint4*)(Yb + (size_t)gr * N + bn + un * 8) =
                    *(const uint4*)(Cs + row * 256 + (u << 4));
            }
        }
    }
}

// ---------------------------------------------------------------- fused edge phase
// NODE-CHUNKED stateless variant: processes node n iff rowptr[n] in [e0, elim).

__global__ __launch_bounds__(128) void k_edge_fc(
    const ushort_t* __restrict__ qkvs, const ushort_t* __restrict__ eb,
    const int* __restrict__ psrc, const int* __restrict__ rowptr,
    ushort_t* __restrict__ xoutb, int e0, int elim) {
    int n = blockIdx.x;
    int beg = rowptr[n], end = rowptr[n + 1];
    if (beg < e0 || beg >= elim) return;

    int t = threadIdx.x;
    int w = t >> 6;
    int lane = t & 63;
    int c0 = lane * 8;
    int h = lane >> 2;

    float q[8];
    unpack8(*(const uint4*)(qkvs + (size_t)n * NCAT + c0), q);

    float mm = -1e30f, dd = 0.f, a[8];
#pragma unroll
    for (int j = 0; j < 8; ++j) a[j] = 0.f;

    int i = beg + w;
    uint4 ku4, vu4, eu4;
    if (i < end) {
        int sn = psrc[i];
        ku4 = *(const uint4*)(qkvs + (size_t)sn * NCAT + 512 + c0);
        vu4 = *(const uint4*)(qkvs + (size_t)sn * NCAT + 1024 + c0);
        eu4 = *(const uint4*)(eb + (size_t)(i - e0) * HC + c0);
    }
    while (i < end) {
        uint4 kc = ku4, vc = vu4, ec = eu4;
        int inext = i + 2;
        if (inext < end) {
            int sn2 = psrc[inext];
            ku4 = *(const uint4*)(qkvs + (size_t)sn2 * NCAT + 512 + c0);
            vu4 = *(const uint4*)(qkvs + (size_t)sn2 * NCAT + 1024 + c0);
            eu4 = *(const uint4*)(eb + (size_t)(inext - e0) * HC + c0);
        }
        float kk[8], vv[8], ee[8];
        unpack8(kc, kk); unpack8(vc, vv); unpack8(ec, ee);
        float part = 0.f;
#pragma unroll
        for (int j = 0; j < 8; ++j) part += q[j] * (kk[j] + ee[j]);
        part += __shfl_xor(part, 1);
        part += __shfl_xor(part, 2);
        float s = part * 0.17677669529663687f;   // /sqrt(32)
        float mn = fmaxf(mm, s);
        float sc = __expf(mm - mn);
        float p  = __expf(s - mn);
        dd = dd * sc + p;
        mm = mn;
#pragma unroll
        for (int j = 0; j < 8; ++j) a[j] = a[j] * sc + p * (vv[j] + ee[j]);
        i = inext;
    }

    __shared__ float sm_acc[512];
    __shared__ float sm_m[16];
    __shared__ float sm_d[16];
    if (w == 1) {
#pragma unroll
        for (int j = 0; j < 8; ++j) sm_acc[c0 + j] = a[j];
        if ((lane & 3) == 0) { sm_m[h] = mm; sm_d[h] = dd; }
    }
    __syncthreads();
    if (w == 0) {
        float m1 = sm_m[h], d1 = sm_d[h];
        float M = fmaxf(mm, m1);
        float sc0 = __expf(mm - M);
        float sc1 = __expf(m1 - M);
        dd = dd * sc0 + d1 * sc1;
        float inv = (dd > 0.f) ? 1.f / dd : 0.f;
        float sk[8];
        unpack8(*(const uint4*)(qkvs + (size_t)n * NCAT + 1536 + c0), sk);
        float o[8];
#pragma unroll
        for (int j = 0; j < 8; ++j) {
            float msg = (a[j] * sc0 + sm_acc[c0 + j] * sc1) * inv;
            float v = msg + sk[j];
            o[j] = v >= 0.f ? v : 0.2f * v;
        }
        *(uint4*)(xoutb + (size_t)n * HC + c0) = packf8(o);
    }
}

// ---------------------------------------------------------------- pooling (bf16 in)

__global__ __launch_bounds__(256) void k_pool2(
    const ushort_t* __restrict__ xb, const int* __restrict__ batch,
    float* __restrict__ psum_p, float* __restrict__ pmax_p, int* __restrict__ cnt) {
    int b = blockIdx.x;
    int s = blockIdx.y;
    int lo = 0, hi = N_NODES;
    while (lo < hi) { int mid = (lo + hi) >> 1; if (batch[mid] < b) lo = mid + 1; else hi = mid; }
    int beg = lo;
    hi = N_NODES;
    while (lo < hi) { int mid = (lo + hi) >> 1; if (batch[mid] < b + 1) lo = mid + 1; else hi = mid; }
    int end = lo;
    if (s == 0 && threadIdx.x == 0) cnt[b] = end - beg;
    int cn = end - beg;
    int per = (cn + NSLICE - 1) / NSLICE;
    int nb = beg + s * per;
    int ne = nb + per; if (ne > end) ne = end;
    int c0 = threadIdx.x * 2;
    float s0 = 0.f, s1 = 0.f, m0 = -1e30f, m1 = -1e30f;
    for (int n = nb; n < ne; ++n) {
        unsigned int v = *(const unsigned int*)(xb + (size_t)n * HC + c0);
        float v0 = bf2f((ushort_t)(v & 0xffff));
        float v1 = bf2f((ushort_t)(v >> 16));
        s0 += v0; s1 += v1;
        m0 = fmaxf(m0, v0); m1 = fmaxf(m1, v1);
    }
    size_t o = ((size_t)s * NB + b) * HC + c0;
    psum_p[o] = s0; psum_p[o + 1] = s1;
    pmax_p[o] = m0; pmax_p[o + 1] = m1;
}

__global__ void k_poolfin(const float* __restrict__ psum_p, const float* __restrict__ pmax_p,
                          const int* __restrict__ cnt, float* __restrict__ hsum, int mode) {
    int i = blockIdx.x * blockDim.x + threadIdx.x;
    if (i >= NB * 1024) return;
    int b = i >> 10, c = i & 1023;
    float val;
    if (c < HC) {
        float s = 0.f;
#pragma unroll
        for (int sl = 0; sl < NSLICE; ++sl)
            s += psum_p[((size_t)sl * NB + b) * HC + c];
        int ct = cnt[b];
        val = s / (float)(ct > 0 ? ct : 1);
    } else {
        int cc = c - HC;
        float m = -1e30f;
#pragma unroll
        for (int sl = 0; sl < NSLICE; ++sl)
            m = fmaxf(m, pmax_p[((size_t)sl * NB + b) * HC + cc]);
        val = m;
    }
    if (mode == 0) hsum[i] = val;
    else hsum[i] += val;
}

// ---------------------------------------------------------------- MLP head

__global__ __launch_bounds__(256) void k_head(
    const float* __restrict__ hsum, const float* __restrict__ fc1W,
    const float* __restrict__ fc1b, const float* __restrict__ fc2W,
    const float* __restrict__ fc2b, float* __restrict__ out) {
    int b = blockIdx.x;
    int j = threadIdx.x;
    __shared__ float hs[256];
    float acc = fc1b[j];
    const float* hin = hsum + (size_t)b * 1024;
    for (int k = 0; k < 1024; ++k) {
        acc += hin[k] * fc1W[(size_t)k * 256 + j];
    }
    hs[j] = fmaxf(acc, 0.f);
    __syncthreads();
    if (j < 32) {
        float o = fc2b[j];
        for (int k = 0; k < 256; ++k) o += hs[k] * fc2W[(size_t)k * 32 + j];
        out[b * 32 + j] = o;
    }
}

// ---------------------------------------------------------------- driver

extern "C" void kernel_launch(void* const* d_in, const int* in_sizes, int n_in,
                              void* d_out, int out_size, void* d_ws, size_t ws_size,
                              hipStream_t stream) {
    const float* x      = (const float*)d_in[0];
    const float* ea     = (const float*)d_in[1];
    const int*   ei     = (const int*)d_in[2];
    const int*   batch  = (const int*)d_in[3];
    const int* src = ei;
    const int* dst = ei + N_EDGES;

    const float* t1_Wq = (const float*)d_in[4];
    const float* t1_bq = (const float*)d_in[5];
    const float* t1_Wk = (const float*)d_in[6];
    const float* t1_bk = (const float*)d_in[7];
    const float* t1_Wv = (const float*)d_in[8];
    const float* t1_bv = (const float*)d_in[9];
    const float* t1_We = (const float*)d_in[10];
    const float* t1_Ws = (const float*)d_in[11];
    const float* t1_bs = (const float*)d_in[12];
    const float* t2_Wq = (const float*)d_in[13];
    const float* t2_bq = (const float*)d_in[14];
    const float* t2_Wk = (const float*)d_in[15];
    const float* t2_bk = (const float*)d_in[16];
    const float* t2_Wv = (const float*)d_in[17];
    const float* t2_bv = (const float*)d_in[18];
    const float* t2_We = (const float*)d_in[19];
    const float* t2_Ws = (const float*)d_in[20];
    const float* t2_bs = (const float*)d_in[21];
    const float* fc1_W = (const float*)d_in[22];
    const float* fc1_b = (const float*)d_in[23];
    const float* fc2_W = (const float*)d_in[24];
    const float* fc2_b = (const float*)d_in[25];

    char* ws = (char*)d_ws;
    size_t off = 0;
    auto alloc = [&](size_t bytes) -> void* {
        void* p = ws + off;
        off = (off + bytes + 255) & ~(size_t)255;
        return p;
    };

    // ---- fixed buffers ----
    ushort_t* qkvs = (ushort_t*)alloc((size_t)N_NODES * NCAT * 2);  // q|k|v|skip bf16
    float* psum_p = (float*)alloc((size_t)NSLICE * NB * HC * 4);
    float* pmax_p = (float*)alloc((size_t)NSLICE * NB * HC * 4);
    float* hsum = (float*)alloc((size_t)NB * 1024 * 4);
    int*   cnt  = (int*)alloc((size_t)NB * 4);
    int* deg    = (int*)alloc((size_t)N_NODES * 4);
    int* rowptr = (int*)alloc((size_t)(N_NODES + 1) * 4);
    int* cursor = (int*)alloc((size_t)N_NODES * 4);
    int* perm   = (int*)alloc((size_t)N_EDGES * 4);
    int* psrc   = (int*)alloc((size_t)N_EDGES * 4);
    ushort_t* x_b  = (ushort_t*)alloc((size_t)N_NODES * IN_CH * 2);
    ushort_t* x1_b = (ushort_t*)alloc((size_t)N_NODES * HC * 2);
    ushort_t* ea_b = (ushort_t*)alloc((size_t)N_EDGES * EDP * 2 + 256);  // +tail slack
    ushort_t* wcat1 = (ushort_t*)alloc((size_t)NCAT * IN_CH * 2);
    ushort_t* wcat2 = (ushort_t*)alloc((size_t)NCAT * HC * 2);
    ushort_t* w_e   = (ushort_t*)alloc((size_t)2 * HC * KEP * 2);  // [2][HC][128] zero-pad
    float* bcat = (float*)alloc((size_t)2 * NCAT * 4);             // [2][NCAT]

    // ---- eb: node-chunked edge window (R25 single-buffer scheme) ----
    size_t remain = (ws_size > off) ? (ws_size - off) : 0;
    ushort_t* eb = (ushort_t*)(ws + off);
    size_t per_edge = (size_t)HC * 2;                // 1 KiB per edge row
    long cap_rows = (long)(remain / per_edge);
    long S_max = cap_rows - DEGSLK;
    if (S_max < 1024) S_max = 1024;                  // degenerate guard
    int nch = (int)((N_EDGES + S_max - 1) / S_max);
    if (nch < 1) nch = 1;
    int S = (N_EDGES + nch - 1) / nch;               // node-chunk stride in edges
    (void)in_sizes; (void)n_in; (void)out_size;

    // ---- CSR build (before ea conversion: k_cvt_ea uses perm)
    hipLaunchKernelGGL(k_zero_i, dim3(79), dim3(256), 0, stream, deg, N_NODES);
    hipLaunchKernelGGL(k_hist, dim3((N_EDGES + 255) / 256), dim3(256), 0, stream, dst, deg);
    hipLaunchKernelGGL(k_scan, dim3(1), dim3(1024), 0, stream, deg, rowptr, cursor);
    hipLaunchKernelGGL(k_scatter, dim3((N_EDGES + 255) / 256), dim3(256), 0, stream,
                       src, dst, cursor, perm, psrc);

    // ---- conversions
    hipLaunchKernelGGL(k_cvt_x, dim3(512), dim3(256), 0, stream, x, x_b,
                       N_NODES * IN_CH / 8);
    hipLaunchKernelGGL(k_cvt_ea, dim3(4096), dim3(256), 0, stream, ea, perm, ea_b);
    // zero 256B tail slack of ea_b (edge GEMM A-overflow reads must be finite)
    hipLaunchKernelGGL(k_zero_i, dim3(1), dim3(64), 0, stream,
                       (int*)(ea_b + (size_t)N_EDGES * EDP), 64);
    hipLaunchKernelGGL(k_cvt_wtT, dim3(HC / 32, IN_CH / 32, 4), dim3(256), 0, stream,
                       t1_Wq, t1_Wk, t1_Wv, t1_Ws, wcat1, IN_CH, HC, IN_CH);
    hipLaunchKernelGGL(k_cvt_wtT, dim3(HC / 32, HC / 32, 4), dim3(256), 0, stream,
                       t2_Wq, t2_Wk, t2_Wv, t2_Ws, wcat2, HC, HC, HC);
    hipLaunchKernelGGL(k_cvt_wtT, dim3(HC / 32, KEP / 32, 2), dim3(256), 0, stream,
                       t1_We, t2_We, t1_We, t1_We, w_e, ED, HC, KEP);
    hipLaunchKernelGGL(k_bcat2, dim3(16), dim3(256), 0, stream,
                       t1_bq, t1_bk, t1_bv, t1_bs, t2_bq, t2_bk, t2_bv, t2_bs, bcat);

    auto run_layer = [&](const ushort_t* xin_b, int Kin, const ushort_t* wcat,
                         const float* bc, const ushort_t* we,
                         ushort_t* xoutb, int poolmode) {
        int mt = (N_NODES + 127) / 128;
        int nt = NCAT / 128;
        int nq = mt * nt;                            // 2512

        // chunk 0 fused with QKVS (unified body)
        long ecl0 = (long)S + DEGSLK;
        if (ecl0 > N_EDGES) ecl0 = N_EDGES;
        int ecnt0 = (int)ecl0;
        int neg0 = ((ecnt0 + 127) / 128) * 4;
        hipLaunchKernelGGL(k_mega, dim3(nq + neg0), dim3(256), 0, stream,
                           xin_b, wcat, bc, qkvs, N_NODES, Kin, NCAT, nq,
                           ea_b, we, eb, ecnt0, neg0);
        {
            int elim0 = (nch == 1) ? (N_EDGES + 1) : S;
            hipLaunchKernelGGL(k_edge_fc, dim3(N_NODES), dim3(128), 0, stream,
                               qkvs, eb, psrc, rowptr, xoutb, 0, elim0);
        }
        for (int ci = 1; ci < nch; ++ci) {
            int e0 = ci * S;
            if (e0 >= N_EDGES) break;
            long ecl = (long)S + DEGSLK;
            if (ecl > N_EDGES - e0) ecl = N_EDGES - e0;
            int ecnt = (int)ecl;
            int gm = (ecnt + 127) / 128;
            hipLaunchKernelGGL(k_mfma_gemm, dim3(gm * 4), dim3(256), 0, stream,
                               ea_b + (size_t)e0 * EDP, EDP, we, KEP,
                               (const float*)nullptr, eb, ecnt, KEP, HC);
            int elim = (ci == nch - 1) ? (N_EDGES + 1) : (e0 + S);
            hipLaunchKernelGGL(k_edge_fc, dim3(N_NODES), dim3(128), 0, stream,
                               qkvs, eb, psrc, rowptr, xoutb, e0, elim);
        }

        // pooling (bf16 input, atomic-free partials)
        hipLaunchKernelGGL(k_pool2, dim3(NB, NSLICE), dim3(256), 0, stream,
                           xoutb, batch, psum_p, pmax_p, cnt);
        hipLaunchKernelGGL(k_poolfin, dim3((NB * 1024 + 255) / 256), dim3(256), 0, stream,
                           psum_p, pmax_p, cnt, hsum, poolmode);
    };

    // layer 1: x_b (N,128) -> x1_b ; layer 2: x1_b (N,512) -> x1_b
    run_layer(x_b, IN_CH, wcat1, bcat, w_e, x1_b, /*poolmode=*/0);
    run_layer(x1_b, HC, wcat2, bcat + NCAT, w_e + (size_t)HC * KEP, x1_b, /*poolmode=*/1);

    hipLaunchKernelGGL(k_head, dim3(NB), dim3(256), 0, stream,
                       hsum, fc1_W, fc1_b, fc2_W, fc2_b, (float*)d_out);
}

// Round 28
// 540.403 us; speedup vs baseline: 1.0863x; 1.0685x over previous
//
#include <hip/hip_runtime.h>
#include <cstdint>
#include <cstddef>

#define N_NODES 20000
#define N_EDGES 160000
#define IN_CH   128
#define NH      16
#define CD      32
#define HC      512   // NH*CD
#define ED      93
#define EDP     96    // ED padded to multiple of 32
#define NB      64
#define NCAT    2048  // q|k|v|skip GEMM output cols (all bf16)
#define NSLICE  8
#define ECSLK   2048  // edge-count slack per node-chunk (>=7 sigma of binomial split)

typedef __attribute__((ext_vector_type(8))) short short8;
typedef __attribute__((ext_vector_type(4))) float f32x4;
typedef unsigned short ushort_t;

// ---------------------------------------------------------------- utilities

__device__ inline ushort_t f2bf(float f) {
    unsigned int u = __float_as_uint(f);
    u = (u + 0x7FFF + ((u >> 16) & 1)) >> 16;   // RNE
    return (ushort_t)u;
}
__device__ inline float bf2f(ushort_t u) {
    return __uint_as_float((unsigned)u << 16);
}
__device__ inline void unpack8(uint4 u, float* o) {
    o[0] = bf2f((ushort_t)(u.x & 0xffff)); o[1] = bf2f((ushort_t)(u.x >> 16));
    o[2] = bf2f((ushort_t)(u.y & 0xffff)); o[3] = bf2f((ushort_t)(u.y >> 16));
    o[4] = bf2f((ushort_t)(u.z & 0xffff)); o[5] = bf2f((ushort_t)(u.z >> 16));
    o[6] = bf2f((ushort_t)(u.w & 0xffff)); o[7] = bf2f((ushort_t)(u.w >> 16));
}
__device__ inline uint4 packf8(const float* f) {
    uint4 u;
    u.x = (unsigned)f2bf(f[0]) | ((unsigned)f2bf(f[1]) << 16);
    u.y = (unsigned)f2bf(f[2]) | ((unsigned)f2bf(f[3]) << 16);
    u.z = (unsigned)f2bf(f[4]) | ((unsigned)f2bf(f[5]) << 16);
    u.w = (unsigned)f2bf(f[6]) | ((unsigned)f2bf(f[7]) << 16);
    return u;
}

// async global->LDS, 16B per lane; lds dest = wave-uniform base + lane*16
__device__ inline void gload_lds16(const void* g, void* l) {
    __builtin_amdgcn_global_load_lds(
        (const __attribute__((address_space(1))) void*)g,
        (__attribute__((address_space(3))) void*)l, 16, 0, 0);
}

__global__ void k_zero_i(int* __restrict__ p, int n) {
    int i = blockIdx.x * blockDim.x + threadIdx.x;
    int stride = gridDim.x * blockDim.x;
    for (; i < n; i += stride) p[i] = 0;
}

// x f32 -> bf16, 8 elems/thread vectorized (n % 8 == 0)
__global__ void k_cvt_x(const float* __restrict__ in, ushort_t* __restrict__ out, int n8) {
    int i = blockIdx.x * blockDim.x + threadIdx.x;
    int stride = gridDim.x * blockDim.x;
    for (; i < n8; i += stride) {
        const float4* p = (const float4*)(in + (size_t)i * 8);
        float4 a = p[0], b = p[1];
        float f[8] = {a.x, a.y, a.z, a.w, b.x, b.y, b.z, b.w};
        *(uint4*)(out + (size_t)i * 8) = packf8(f);
    }
}

// edge_attr [E,93] f32 -> PERMUTED [E,96] bf16: out row p = in row perm[p].
__global__ void k_cvt_ea(const float* __restrict__ in, const int* __restrict__ perm,
                         ushort_t* __restrict__ out) {
    int i = blockIdx.x * blockDim.x + threadIdx.x;
    int stride = gridDim.x * blockDim.x;
    int total = N_EDGES * EDP;
    for (; i < total; i += stride) {
        int p = i / EDP, k = i - p * EDP;
        int e = perm[p];
        out[i] = (k < ED) ? f2bf(in[(size_t)e * ED + k]) : (ushort_t)0;
    }
}

// LDS-tiled transposed weight conversion
__global__ __launch_bounds__(256) void k_cvt_wtT(
    const float* __restrict__ W0, const float* __restrict__ W1,
    const float* __restrict__ W2, const float* __restrict__ W3,
    ushort_t* __restrict__ Wt, int K, int N, int Kp) {
    __shared__ float tile[32][33];
    int z = blockIdx.z;
    const float* W = (z == 0) ? W0 : (z == 1) ? W1 : (z == 2) ? W2 : W3;
    ushort_t* out = Wt + (size_t)z * N * Kp;
    int n0 = blockIdx.x << 5;
    int k0 = blockIdx.y << 5;
    int r = threadIdx.x >> 5;   // 0..7
    int c = threadIdx.x & 31;
#pragma unroll
    for (int rr = 0; rr < 4; ++rr) {
        int k = k0 + r + rr * 8;
        tile[r + rr * 8][c] = (k < K) ? W[(size_t)k * N + n0 + c] : 0.f;
    }
    __syncthreads();
#pragma unroll
    for (int rr = 0; rr < 4; ++rr) {
        int n = n0 + r + rr * 8;
        out[(size_t)n * Kp + k0 + c] = f2bf(tile[c][r + rr * 8]);
    }
}

// bcat[2][2048] = (bq|bk|bv|bs) per layer, one dispatch
__global__ void k_bcat2(
    const float* __restrict__ b0q, const float* __restrict__ b0k,
    const float* __restrict__ b0v, const float* __restrict__ b0s,
    const float* __restrict__ b1q, const float* __restrict__ b1k,
    const float* __restrict__ b1v, const float* __restrict__ b1s,
    float* __restrict__ out) {
    int i = blockIdx.x * blockDim.x + threadIdx.x;
    if (i >= 2 * NCAT) return;
    int l = i >> 11, j = i & (NCAT - 1);
    int s = j >> 9, jj = j & 511;
    const float* b = (l == 0)
        ? ((s == 0) ? b0q : (s == 1) ? b0k : (s == 2) ? b0v : b0s)
        : ((s == 0) ? b1q : (s == 1) ? b1k : (s == 2) ? b1v : b1s);
    out[i] = b[jj];
}

// ---------------------------------------------------------------- CSR build

__global__ void k_hist(const int* __restrict__ dst, int* __restrict__ deg) {
    int i = blockIdx.x * blockDim.x + threadIdx.x;
    if (i < N_EDGES) atomicAdd(&deg[dst[i]], 1);
}

__global__ __launch_bounds__(1024) void k_scan(const int* __restrict__ deg,
                                               int* __restrict__ rowptr,
                                               int* __restrict__ cursor) {
    __shared__ int part[1024];
    int t = threadIdx.x;
    int base = t * 20;
    int loc[20];
    int s = 0;
#pragma unroll
    for (int i = 0; i < 20; ++i) {
        int idx = base + i;
        int v = (idx < N_NODES) ? deg[idx] : 0;
        loc[i] = s; s += v;
    }
    part[t] = s;
    __syncthreads();
    for (int off = 1; off < 1024; off <<= 1) {
        int v = (t >= off) ? part[t - off] : 0;
        __syncthreads();
        part[t] += v;
        __syncthreads();
    }
    int pre = (t > 0) ? part[t - 1] : 0;
#pragma unroll
    for (int i = 0; i < 20; ++i) {
        int idx = base + i;
        if (idx < N_NODES) {
            int v = pre + loc[i];
            rowptr[idx] = v;
            cursor[idx] = v;
        }
    }
    if (t == 1023) rowptr[N_NODES] = part[1023];
}

__global__ void k_scatter(const int* __restrict__ src, const int* __restrict__ dst,
                          int* __restrict__ cursor, int* __restrict__ perm,
                          int* __restrict__ psrc) {
    int i = blockIdx.x * blockDim.x + threadIdx.x;
    if (i >= N_EDGES) return;
    int d = dst[i];
    int p = atomicAdd(&cursor[d], 1);
    perm[p] = i;
    psrc[p] = src[i];
}

// ---------------------------------------------------------------- MEGA kernel
// blocks [0,nq): QKVS GEMM; blocks [nq,nq+neg): edge-GEMM for nodes [0,n1):
// edges [0, rowptr[n1]) (device-read bound). Bodies inline verbatim.

__global__ __launch_bounds__(256) void k_mega(
    const ushort_t* __restrict__ A, const ushort_t* __restrict__ Bt,
    const float* __restrict__ bias, ushort_t* __restrict__ Yb,
    int M, int K, int N, int nq,
    const ushort_t* __restrict__ Ab, const ushort_t* __restrict__ Bte,
    ushort_t* __restrict__ Ybe, const int* __restrict__ rowptrd, int n1, int neg) {
    __shared__ char smem[49152];
    int tid  = threadIdx.x;
    int lane = tid & 63, wave = tid >> 6;
    int l15 = lane & 15, lg = lane >> 4;
    int wm = (wave >> 1) * 64, wn = (wave & 1) * 64;

    if ((int)blockIdx.x < nq) {
        // ---------------- QKVS body ----------------
        char* As = smem;
        char* Bs = smem + 16384;
        int nt = N >> 7;
        int bid = blockIdx.x;
        int wg;
        if ((nq & 7) == 0) { int cpx = nq >> 3; wg = (bid & 7) * cpx + (bid >> 3); }
        else wg = bid;
        int bm = (wg / nt) * 128, bn = (wg % nt) * 128;

        f32x4 acc[4][4] = {};

        int sr = lane >> 3;
        int su = lane & 7;
        int gu = su ^ sr;

        for (int k0 = 0; k0 < K; k0 += 64) {
#pragma unroll
            for (int i = 0; i < 4; ++i) {
                int rloc = wave * 32 + i * 8;
                int row = rloc + sr;
                if (bm + row < M)
                    gload_lds16(A + (size_t)(bm + row) * K + k0 + gu * 8, As + rloc * 128);
                gload_lds16(Bt + (size_t)(bn + row) * K + k0 + gu * 8, Bs + rloc * 128);
            }
            __syncthreads();

#pragma unroll
            for (int ks = 0; ks < 2; ++ks) {
                short8 af[4], bfr[4];
#pragma unroll
                for (int mr = 0; mr < 4; ++mr) {
                    int r = wm + mr * 16 + l15;
                    af[mr] = *(const short8*)(As + r * 128 + (((ks * 4 + lg) ^ (r & 7)) << 4));
                }
#pragma unroll
                for (int nc = 0; nc < 4; ++nc) {
                    int r = wn + nc * 16 + l15;
                    bfr[nc] = *(const short8*)(Bs + r * 128 + (((ks * 4 + lg) ^ (r & 7)) << 4));
                }
#pragma unroll
                for (int mr = 0; mr < 4; ++mr)
#pragma unroll
                    for (int nc = 0; nc < 4; ++nc)
                        acc[mr][nc] = __builtin_amdgcn_mfma_f32_16x16x32_bf16(
                            af[mr], bfr[nc], acc[mr][nc], 0, 0, 0);
            }
            __syncthreads();
        }

        char* Cs = smem;
#pragma unroll
        for (int mr = 0; mr < 4; ++mr) {
#pragma unroll
            for (int nc = 0; nc < 4; ++nc) {
                int coll = wn + nc * 16 + l15;
                float b = bias ? bias[bn + coll] : 0.f;
                int u0 = coll >> 3;
#pragma unroll
                for (int j = 0; j < 4; ++j) {
                    int row = wm + mr * 16 + lg * 4 + j;
                    int u = u0 ^ (row & 7);
                    *(ushort_t*)(Cs + row * 256 + (u << 4) + ((coll & 7) << 1)) =
                        f2bf(acc[mr][nc][j] + b);
                }
            }
        }
        __syncthreads();
        {
            int rsub = tid >> 4;
            int un   = tid & 15;
#pragma unroll
            for (int i = 0; i < 8; ++i) {
                int row = i * 16 + rsub;
                int gr = bm + row;
                if (gr < M) {
                    int u = un ^ (row & 7);
                    *(uint4*)(Yb + (size_t)gr * N + bn + un * 8) =
                        *(const uint4*)(Cs + row * 256 + (u << 4));
                }
            }
        }
    } else {
        // ---------------- edge-GEMM body (chunk 0: pbase = 0, ec from rowptr) ----------------
        int ec = rowptrd[n1];
        char* As = smem;
        char* Bs = smem + 24576;
        int bid = blockIdx.x - nq;
        int wg;
        if ((neg & 7) == 0) { int cpx = neg >> 3; wg = (bid & 7) * cpx + (bid >> 3); }
        else wg = bid;
        int bm = (wg >> 2) * 128;
        int n0 = (wg & 3) * 128;

        int srow = tid >> 1;
        int h    = tid & 1;
        int ssw  = ((srow >> 1) & 3) << 4;
        {
            int gm = bm + srow;
            uint4 va[6];
#pragma unroll
            for (int i = 0; i < 6; ++i) { va[i].x = va[i].y = va[i].z = va[i].w = 0; }
            if (gm < ec) {
                const uint4* ga = (const uint4*)(Ab + (size_t)gm * EDP + h * 48);
#pragma unroll
                for (int i = 0; i < 6; ++i) va[i] = ga[i];
            }
            char* dsta = As + srow * 192;
#pragma unroll
            for (int i = 0; i < 6; ++i) {
                int c = h * 96 + i * 16;
                *(uint4*)(dsta + ((c & ~63) | ((c & 63) ^ ssw))) = va[i];
            }
            uint4 vb[6];
            {
                const uint4* gb = (const uint4*)(Bte + (size_t)(n0 + srow) * EDP + h * 48);
#pragma unroll
                for (int i = 0; i < 6; ++i) vb[i] = gb[i];
            }
            char* dstb = Bs + srow * 192;
#pragma unroll
            for (int i = 0; i < 6; ++i) {
                int c = h * 96 + i * 16;
                *(uint4*)(dstb + ((c & ~63) | ((c & 63) ^ ssw))) = vb[i];
            }
        }
        __syncthreads();

        int fsw = ((l15 >> 1) & 3) << 4;

        f32x4 acc[4][4] = {};
#pragma unroll
        for (int ks = 0; ks < 3; ++ks) {
            short8 af[4], bfr[4];
#pragma unroll
            for (int mr = 0; mr < 4; ++mr) {
                int r = wm + mr * 16 + l15;
                int c = ks * 64 + ((lg * 16) ^ fsw);
                af[mr] = *(const short8*)(As + r * 192 + c);
            }
#pragma unroll
            for (int nc = 0; nc < 4; ++nc) {
                int r = wn + nc * 16 + l15;
                int c = ks * 64 + ((lg * 16) ^ fsw);
                bfr[nc] = *(const short8*)(Bs + r * 192 + c);
            }
#pragma unroll
            for (int mr = 0; mr < 4; ++mr)
#pragma unroll
                for (int nc = 0; nc < 4; ++nc)
                    acc[mr][nc] = __builtin_amdgcn_mfma_f32_16x16x32_bf16(
                        af[mr], bfr[nc], acc[mr][nc], 0, 0, 0);
        }
        __syncthreads();

        char* Cs = smem;   // 128 rows * 288B stride = 36864
#pragma unroll
        for (int mr = 0; mr < 4; ++mr) {
#pragma unroll
            for (int nc = 0; nc < 4; ++nc) {
                int col = wn + nc * 16 + l15;
#pragma unroll
                for (int j = 0; j < 4; ++j) {
                    int row = wm + mr * 16 + lg * 4 + j;
                    *(ushort_t*)(Cs + row * 288 + col * 2) = f2bf(acc[mr][nc][j]);
                }
            }
        }
        __syncthreads();

        {
            int rsub = tid >> 4;
            int un   = tid & 15;
#pragma unroll
            for (int i = 0; i < 8; ++i) {
                int row = i * 16 + rsub;
                if (bm + row < ec) {
                    *(uint4*)(Ybe + (size_t)(bm + row) * HC + n0 + un * 8) =
                        *(const uint4*)(Cs + row * 288 + un * 16);
                }
            }
        }
    }
}

// ---------------------------------------------------------------- standalone QKVS
// (kept only for codegen isolation; not launched in normal path)

__global__ __launch_bounds__(256) void k_mfma_gemm(
    const ushort_t* __restrict__ A, const ushort_t* __restrict__ Bt,
    const float* __restrict__ bias, ushort_t* __restrict__ Yb,
    int M, int K, int N) {
    __shared__ char smem[32768];
    char* As = smem;
    char* Bs = smem + 16384;

    int tid  = threadIdx.x;
    int lane = tid & 63, wave = tid >> 6;
    int l15 = lane & 15, lg = lane >> 4;
    int nt = N >> 7;
    int nwg = gridDim.x;
    int bid = blockIdx.x;
    int wg;
    if ((nwg & 7) == 0) { int cpx = nwg >> 3; wg = (bid & 7) * cpx + (bid >> 3); }
    else wg = bid;
    int bm = (wg / nt) * 128, bn = (wg % nt) * 128;
    int wm = (wave >> 1) * 64, wn = (wave & 1) * 64;

    f32x4 acc[4][4] = {};

    int sr = lane >> 3;
    int su = lane & 7;
    int gu = su ^ sr;

    for (int k0 = 0; k0 < K; k0 += 64) {
#pragma unroll
        for (int i = 0; i < 4; ++i) {
            int rloc = wave * 32 + i * 8;
            int row = rloc + sr;
            if (bm + row < M)
                gload_lds16(A + (size_t)(bm + row) * K + k0 + gu * 8, As + rloc * 128);
            gload_lds16(Bt + (size_t)(bn + row) * K + k0 + gu * 8, Bs + rloc * 128);
        }
        __syncthreads();

#pragma unroll
        for (int ks = 0; ks < 2; ++ks) {
            short8 af[4], bfr[4];
#pragma unroll
            for (int mr = 0; mr < 4; ++mr) {
                int r = wm + mr * 16 + l15;
                af[mr] = *(const short8*)(As + r * 128 + (((ks * 4 + lg) ^ (r & 7)) << 4));
            }
#pragma unroll
            for (int nc = 0; nc < 4; ++nc) {
                int r = wn + nc * 16 + l15;
                bfr[nc] = *(const short8*)(Bs + r * 128 + (((ks * 4 + lg) ^ (r & 7)) << 4));
            }
#pragma unroll
            for (int mr = 0; mr < 4; ++mr)
#pragma unroll
                for (int nc = 0; nc < 4; ++nc)
                    acc[mr][nc] = __builtin_amdgcn_mfma_f32_16x16x32_bf16(
                        af[mr], bfr[nc], acc[mr][nc], 0, 0, 0);
        }
        __syncthreads();
    }

    char* Cs = smem;
#pragma unroll
    for (int mr = 0; mr < 4; ++mr) {
#pragma unroll
        for (int nc = 0; nc < 4; ++nc) {
            int coll = wn + nc * 16 + l15;
            float b = bias ? bias[bn + coll] : 0.f;
            int u0 = coll >> 3;
#pragma unroll
            for (int j = 0; j < 4; ++j) {
                int row = wm + mr * 16 + lg * 4 + j;
                int u = u0 ^ (row & 7);
                *(ushort_t*)(Cs + row * 256 + (u << 4) + ((coll & 7) << 1)) =
                    f2bf(acc[mr][nc][j] + b);
            }
        }
    }
    __syncthreads();
    {
        int rsub = tid >> 4;
        int un   = tid & 15;
#pragma unroll
        for (int i = 0; i < 8; ++i) {
            int row = i * 16 + rsub;
            int gr = bm + row;
            if (gr < M) {
                int u = un ^ (row & 7);
                *(uint4*)(Yb + (size_t)gr * N + bn + un * 8) =
                    *(const uint4*)(Cs + row * 256 + (u << 4));
            }
        }
    }
}

// ---------------------------------------------------------------- edge GEMM
// eb[r-pbase, :512] = ea_b[r, :96] @ We[512,96]^T for r in [rowptr[nlo], rowptr[nhi]).

__global__ __launch_bounds__(256) void k_egemm(
    const ushort_t* __restrict__ Ab, const ushort_t* __restrict__ Bt,
    ushort_t* __restrict__ Yb, const int* __restrict__ rowptrd,
    int nlo, int nhi) {
    __shared__ char smem[49152];
    char* As = smem;
    char* Bs = smem + 24576;

    int pbase = rowptrd[nlo];
    int ec    = rowptrd[nhi] - pbase;

    int tid  = threadIdx.x;
    int lane = tid & 63, wave = tid >> 6;
    int l15 = lane & 15, lg = lane >> 4;
    int nwg = gridDim.x;
    int bid = blockIdx.x;
    int wg;
    if ((nwg & 7) == 0) { int cpx = nwg >> 3; wg = (bid & 7) * cpx + (bid >> 3); }
    else wg = bid;
    int bm = (wg >> 2) * 128;
    int n0 = (wg & 3) * 128;
    int wm = (wave >> 1) * 64, wn = (wave & 1) * 64;

    int srow = tid >> 1;
    int h    = tid & 1;
    int ssw  = ((srow >> 1) & 3) << 4;
    {
        int gm = bm + srow;
        uint4 va[6];
#pragma unroll
        for (int i = 0; i < 6; ++i) { va[i].x = va[i].y = va[i].z = va[i].w = 0; }
        if (gm < ec) {
            const uint4* ga = (const uint4*)(Ab + (size_t)(pbase + gm) * EDP + h * 48);
#pragma unroll
            for (int i = 0; i < 6; ++i) va[i] = ga[i];
        }
        char* dsta = As + srow * 192;
#pragma unroll
        for (int i = 0; i < 6; ++i) {
            int c = h * 96 + i * 16;
            *(uint4*)(dsta + ((c & ~63) | ((c & 63) ^ ssw))) = va[i];
        }
        uint4 vb[6];
        {
            const uint4* gb = (const uint4*)(Bt + (size_t)(n0 + srow) * EDP + h * 48);
#pragma unroll
            for (int i = 0; i < 6; ++i) vb[i] = gb[i];
        }
        char* dstb = Bs + srow * 192;
#pragma unroll
        for (int i = 0; i < 6; ++i) {
            int c = h * 96 + i * 16;
            *(uint4*)(dstb + ((c & ~63) | ((c & 63) ^ ssw))) = vb[i];
        }
    }
    __syncthreads();

    int fsw = ((l15 >> 1) & 3) << 4;

    f32x4 acc[4][4] = {};
#pragma unroll
    for (int ks = 0; ks < 3; ++ks) {
        short8 af[4], bfr[4];
#pragma unroll
        for (int mr = 0; mr < 4; ++mr) {
            int r = wm + mr * 16 + l15;
            int c = ks * 64 + ((lg * 16) ^ fsw);
            af[mr] = *(const short8*)(As + r * 192 + c);
        }
#pragma unroll
        for (int nc = 0; nc < 4; ++nc) {
            int r = wn + nc * 16 + l15;
            int c = ks * 64 + ((lg * 16) ^ fsw);
            bfr[nc] = *(const short8*)(Bs + r * 192 + c);
        }
#pragma unroll
        for (int mr = 0; mr < 4; ++mr)
#pragma unroll
            for (int nc = 0; nc < 4; ++nc)
                acc[mr][nc] = __builtin_amdgcn_mfma_f32_16x16x32_bf16(
                    af[mr], bfr[nc], acc[mr][nc], 0, 0, 0);
    }
    __syncthreads();

    char* Cs = smem;   // 128 rows * 288B stride = 36864
#pragma unroll
    for (int mr = 0; mr < 4; ++mr) {
#pragma unroll
        for (int nc = 0; nc < 4; ++nc) {
            int col = wn + nc * 16 + l15;
#pragma unroll
            for (int j = 0; j < 4; ++j) {
                int row = wm + mr * 16 + lg * 4 + j;
                *(ushort_t*)(Cs + row * 288 + col * 2) = f2bf(acc[mr][nc][j]);
            }
        }
    }
    __syncthreads();

    {
        int rsub = tid >> 4;
        int un   = tid & 15;
#pragma unroll
        for (int i = 0; i < 8; ++i) {
            int row = i * 16 + rsub;
            if (bm + row < ec) {
                *(uint4*)(Yb + (size_t)(bm + row) * HC + n0 + un * 8) =
                    *(const uint4*)(Cs + row * 288 + un * 16);
            }
        }
    }
}

// ---------------------------------------------------------------- fused edge phase
// NODE-RANGE variant: block b handles node n = nlo + b (grid = nhi-nlo exactly).
// eb holds edges [rowptr[nlo], ...): full range of every node in chunk by construction.

__global__ __launch_bounds__(128) void k_edge_fc(
    const ushort_t* __restrict__ qkvs, const ushort_t* __restrict__ eb,
    const int* __restrict__ psrc, const int* __restrict__ rowptrd,
    ushort_t* __restrict__ xoutb, int nlo) {
    int n = nlo + blockIdx.x;
    int e0 = rowptrd[nlo];
    int beg = rowptrd[n], end = rowptrd[n + 1];

    int t = threadIdx.x;
    int w = t >> 6;
    int lane = t & 63;
    int c0 = lane * 8;
    int h = lane >> 2;

    float q[8];
    unpack8(*(const uint4*)(qkvs + (size_t)n * NCAT + c0), q);

    float mm = -1e30f, dd = 0.f, a[8];
#pragma unroll
    for (int j = 0; j < 8; ++j) a[j] = 0.f;

    int i = beg + w;
    uint4 ku4, vu4, eu4;
    if (i < end) {
        int sn = psrc[i];
        ku4 = *(const uint4*)(qkvs + (size_t)sn * NCAT + 512 + c0);
        vu4 = *(const uint4*)(qkvs + (size_t)sn * NCAT + 1024 + c0);
        eu4 = *(const uint4*)(eb + (size_t)(i - e0) * HC + c0);
    }
    while (i < end) {
        uint4 kc = ku4, vc = vu4, ec = eu4;
        int inext = i + 2;
        if (inext < end) {
            int sn2 = psrc[inext];
            ku4 = *(const uint4*)(qkvs + (size_t)sn2 * NCAT + 512 + c0);
            vu4 = *(const uint4*)(qkvs + (size_t)sn2 * NCAT + 1024 + c0);
            eu4 = *(const uint4*)(eb + (size_t)(inext - e0) * HC + c0);
        }
        float kk[8], vv[8], ee[8];
        unpack8(kc, kk); unpack8(vc, vv); unpack8(ec, ee);
        float part = 0.f;
#pragma unroll
        for (int j = 0; j < 8; ++j) part += q[j] * (kk[j] + ee[j]);
        part += __shfl_xor(part, 1);
        part += __shfl_xor(part, 2);
        float s = part * 0.17677669529663687f;   // /sqrt(32)
        float mn = fmaxf(mm, s);
        float sc = __expf(mm - mn);
        float p  = __expf(s - mn);
        dd = dd * sc + p;
        mm = mn;
#pragma unroll
        for (int j = 0; j < 8; ++j) a[j] = a[j] * sc + p * (vv[j] + ee[j]);
        i = inext;
    }

    __shared__ float sm_acc[512];
    __shared__ float sm_m[16];
    __shared__ float sm_d[16];
    if (w == 1) {
#pragma unroll
        for (int j = 0; j < 8; ++j) sm_acc[c0 + j] = a[j];
        if ((lane & 3) == 0) { sm_m[h] = mm; sm_d[h] = dd; }
    }
    __syncthreads();
    if (w == 0) {
        float m1 = sm_m[h], d1 = sm_d[h];
        float M = fmaxf(mm, m1);
        float sc0 = __expf(mm - M);
        float sc1 = __expf(m1 - M);
        dd = dd * sc0 + d1 * sc1;
        float inv = (dd > 0.f) ? 1.f / dd : 0.f;
        float sk[8];
        unpack8(*(const uint4*)(qkvs + (size_t)n * NCAT + 1536 + c0), sk);
        float o[8];
#pragma unroll
        for (int j = 0; j < 8; ++j) {
            float msg = (a[j] * sc0 + sm_acc[c0 + j] * sc1) * inv;
            float v = msg + sk[j];
            o[j] = v >= 0.f ? v : 0.2f * v;
        }
        *(uint4*)(xoutb + (size_t)n * HC + c0) = packf8(o);
    }
}

// ---------------------------------------------------------------- pooling (bf16 in)

__global__ __launch_bounds__(256) void k_pool2(
    const ushort_t* __restrict__ xb, const int* __restrict__ batch,
    float* __restrict__ psum_p, float* __restrict__ pmax_p, int* __restrict__ cnt) {
    int b = blockIdx.x;
    int s = blockIdx.y;
    int lo = 0, hi = N_NODES;
    while (lo < hi) { int mid = (lo + hi) >> 1; if (batch[mid] < b) lo = mid + 1; else hi = mid; }
    int beg = lo;
    hi = N_NODES;
    while (lo < hi) { int mid = (lo + hi) >> 1; if (batch[mid] < b + 1) lo = mid + 1; else hi = mid; }
    int end = lo;
    if (s == 0 && threadIdx.x == 0) cnt[b] = end - beg;
    int cn = end - beg;
    int per = (cn + NSLICE - 1) / NSLICE;
    int nb = beg + s * per;
    int ne = nb + per; if (ne > end) ne = end;
    int c0 = threadIdx.x * 2;
    float s0 = 0.f, s1 = 0.f, m0 = -1e30f, m1 = -1e30f;
    for (int n = nb; n < ne; ++n) {
        unsigned int v = *(const unsigned int*)(xb + (size_t)n * HC + c0);
        float v0 = bf2f((ushort_t)(v & 0xffff));
        float v1 = bf2f((ushort_t)(v >> 16));
        s0 += v0; s1 += v1;
        m0 = fmaxf(m0, v0); m1 = fmaxf(m1, v1);
    }
    size_t o = ((size_t)s * NB + b) * HC + c0;
    psum_p[o] = s0; psum_p[o + 1] = s1;
    pmax_p[o] = m0; pmax_p[o + 1] = m1;
}

__global__ void k_poolfin(const float* __restrict__ psum_p, const float* __restrict__ pmax_p,
                          const int* __restrict__ cnt, float* __restrict__ hsum, int mode) {
    int i = blockIdx.x * blockDim.x + threadIdx.x;
    if (i >= NB * 1024) return;
    int b = i >> 10, c = i & 1023;
    float val;
    if (c < HC) {
        float s = 0.f;
#pragma unroll
        for (int sl = 0; sl < NSLICE; ++sl)
            s += psum_p[((size_t)sl * NB + b) * HC + c];
        int ct = cnt[b];
        val = s / (float)(ct > 0 ? ct : 1);
    } else {
        int cc = c - HC;
        float m = -1e30f;
#pragma unroll
        for (int sl = 0; sl < NSLICE; ++sl)
            m = fmaxf(m, pmax_p[((size_t)sl * NB + b) * HC + cc]);
        val = m;
    }
    if (mode == 0) hsum[i] = val;
    else hsum[i] += val;
}

// ---------------------------------------------------------------- MLP head

__global__ __launch_bounds__(256) void k_head(
    const float* __restrict__ hsum, const float* __restrict__ fc1W,
    const float* __restrict__ fc1b, const float* __restrict__ fc2W,
    const float* __restrict__ fc2b, float* __restrict__ out) {
    int b = blockIdx.x;
    int j = threadIdx.x;
    __shared__ float hs[256];
    float acc = fc1b[j];
    const float* hin = hsum + (size_t)b * 1024;
    for (int k = 0; k < 1024; ++k) {
        acc += hin[k] * fc1W[(size_t)k * 256 + j];
    }
    hs[j] = fmaxf(acc, 0.f);
    __syncthreads();
    if (j < 32) {
        float o = fc2b[j];
        for (int k = 0; k < 256; ++k) o += hs[k] * fc2W[(size_t)k * 32 + j];
        out[b * 32 + j] = o;
    }
}

// ---------------------------------------------------------------- driver

extern "C" void kernel_launch(void* const* d_in, const int* in_sizes, int n_in,
                              void* d_out, int out_size, void* d_ws, size_t ws_size,
                              hipStream_t stream) {
    const float* x      = (const float*)d_in[0];
    const float* ea     = (const float*)d_in[1];
    const int*   ei     = (const int*)d_in[2];
    const int*   batch  = (const int*)d_in[3];
    const int* src = ei;
    const int* dst = ei + N_EDGES;

    const float* t1_Wq = (const float*)d_in[4];
    const float* t1_bq = (const float*)d_in[5];
    const float* t1_Wk = (const float*)d_in[6];
    const float* t1_bk = (const float*)d_in[7];
    const float* t1_Wv = (const float*)d_in[8];
    const float* t1_bv = (const float*)d_in[9];
    const float* t1_We = (const float*)d_in[10];
    const float* t1_Ws = (const float*)d_in[11];
    const float* t1_bs = (const float*)d_in[12];
    const float* t2_Wq = (const float*)d_in[13];
    const float* t2_bq = (const float*)d_in[14];
    const float* t2_Wk = (const float*)d_in[15];
    const float* t2_bk = (const float*)d_in[16];
    const float* t2_Wv = (const float*)d_in[17];
    const float* t2_bv = (const float*)d_in[18];
    const float* t2_We = (const float*)d_in[19];
    const float* t2_Ws = (const float*)d_in[20];
    const float* t2_bs = (const float*)d_in[21];
    const float* fc1_W = (const float*)d_in[22];
    const float* fc1_b = (const float*)d_in[23];
    const float* fc2_W = (const float*)d_in[24];
    const float* fc2_b = (const float*)d_in[25];

    char* ws = (char*)d_ws;
    size_t off = 0;
    auto alloc = [&](size_t bytes) -> void* {
        void* p = ws + off;
        off = (off + bytes + 255) & ~(size_t)255;
        return p;
    };

    // ---- fixed buffers ----
    ushort_t* qkvs = (ushort_t*)alloc((size_t)N_NODES * NCAT * 2);  // q|k|v|skip bf16
    float* psum_p = (float*)alloc((size_t)NSLICE * NB * HC * 4);
    float* pmax_p = (float*)alloc((size_t)NSLICE * NB * HC * 4);
    float* hsum = (float*)alloc((size_t)NB * 1024 * 4);
    int*   cnt  = (int*)alloc((size_t)NB * 4);
    int* deg    = (int*)alloc((size_t)N_NODES * 4);
    int* rowptr = (int*)alloc((size_t)(N_NODES + 1) * 4);
    int* cursor = (int*)alloc((size_t)N_NODES * 4);
    int* perm   = (int*)alloc((size_t)N_EDGES * 4);
    int* psrc   = (int*)alloc((size_t)N_EDGES * 4);
    ushort_t* x_b  = (ushort_t*)alloc((size_t)N_NODES * IN_CH * 2);
    ushort_t* x1_b = (ushort_t*)alloc((size_t)N_NODES * HC * 2);
    ushort_t* ea_b = (ushort_t*)alloc((size_t)N_EDGES * EDP * 2);   // dst-sorted
    ushort_t* wcat1 = (ushort_t*)alloc((size_t)NCAT * IN_CH * 2);
    ushort_t* wcat2 = (ushort_t*)alloc((size_t)NCAT * HC * 2);
    ushort_t* w_e   = (ushort_t*)alloc((size_t)2 * HC * EDP * 2);  // [2][HC][EDP]
    float* bcat = (float*)alloc((size_t)2 * NCAT * 4);             // [2][NCAT]

    // ---- eb: node-range chunk window, sized from remaining workspace ----
    size_t remain = (ws_size > off) ? (ws_size - off) : 0;
    ushort_t* eb = (ushort_t*)(ws + off);
    size_t per_edge = (size_t)HC * 2;                // 1 KiB per edge row
    long cap_rows = (long)(remain / per_edge);
    int nchN = 1;
    long ecap = N_EDGES;
    if (cap_rows < (long)N_EDGES) {
        nchN = -1;
        for (int c = 2; c <= 64; ++c) {
            long e = (long)(N_EDGES + c - 1) / c + ECSLK;
            if (e <= cap_rows) { nchN = c; ecap = e; break; }
        }
        if (nchN < 0) { nchN = 64; ecap = cap_rows > 1024 ? cap_rows : 1024; }
    }
    int Nc = (N_NODES + nchN - 1) / nchN;            // nodes per chunk
    (void)in_sizes; (void)n_in; (void)out_size;

    // ---- CSR build (before ea conversion: k_cvt_ea uses perm)
    hipLaunchKernelGGL(k_zero_i, dim3(79), dim3(256), 0, stream, deg, N_NODES);
    hipLaunchKernelGGL(k_hist, dim3((N_EDGES + 255) / 256), dim3(256), 0, stream, dst, deg);
    hipLaunchKernelGGL(k_scan, dim3(1), dim3(1024), 0, stream, deg, rowptr, cursor);
    hipLaunchKernelGGL(k_scatter, dim3((N_EDGES + 255) / 256), dim3(256), 0, stream,
                       src, dst, cursor, perm, psrc);

    // ---- conversions
    hipLaunchKernelGGL(k_cvt_x, dim3(512), dim3(256), 0, stream, x, x_b,
                       N_NODES * IN_CH / 8);
    hipLaunchKernelGGL(k_cvt_ea, dim3(4096), dim3(256), 0, stream, ea, perm, ea_b);
    hipLaunchKernelGGL(k_cvt_wtT, dim3(HC / 32, IN_CH / 32, 4), dim3(256), 0, stream,
                       t1_Wq, t1_Wk, t1_Wv, t1_Ws, wcat1, IN_CH, HC, IN_CH);
    hipLaunchKernelGGL(k_cvt_wtT, dim3(HC / 32, HC / 32, 4), dim3(256), 0, stream,
                       t2_Wq, t2_Wk, t2_Wv, t2_Ws, wcat2, HC, HC, HC);
    hipLaunchKernelGGL(k_cvt_wtT, dim3(HC / 32, EDP / 32, 2), dim3(256), 0, stream,
                       t1_We, t2_We, t1_We, t1_We, w_e, ED, HC, EDP);
    hipLaunchKernelGGL(k_bcat2, dim3(16), dim3(256), 0, stream,
                       t1_bq, t1_bk, t1_bv, t1_bs, t2_bq, t2_bk, t2_bv, t2_bs, bcat);

    auto run_layer = [&](const ushort_t* xin_b, int Kin, const ushort_t* wcat,
                         const float* bc, const ushort_t* we,
                         ushort_t* xoutb, int poolmode) {
        int mt = (N_NODES + 127) / 128;
        int nt = NCAT / 128;
        int nq = mt * nt;                            // 2512
        int negc = (int)((ecap + 127) / 128) * 4;    // edge-GEMM grid per chunk

        // chunk 0 (nodes [0, n1)) fused with QKVS
        int n1 = (Nc < N_NODES) ? Nc : N_NODES;
        hipLaunchKernelGGL(k_mega, dim3(nq + negc), dim3(256), 0, stream,
                           xin_b, wcat, bc, qkvs, N_NODES, Kin, NCAT, nq,
                           ea_b, we, eb, rowptr, n1, negc);
        hipLaunchKernelGGL(k_edge_fc, dim3(n1), dim3(128), 0, stream,
                           qkvs, eb, psrc, rowptr, xoutb, 0);

        for (int ci = 1; ci < nchN; ++ci) {
            int nlo = ci * Nc;
            if (nlo >= N_NODES) break;
            int nhi = nlo + Nc; if (nhi > N_NODES) nhi = N_NODES;
            hipLaunchKernelGGL(k_egemm, dim3(negc), dim3(256), 0, stream,
                               ea_b, we, eb, rowptr, nlo, nhi);
            hipLaunchKernelGGL(k_edge_fc, dim3(nhi - nlo), dim3(128), 0, stream,
                               qkvs, eb, psrc, rowptr, xoutb, nlo);
        }

        // pooling (bf16 input, atomic-free partials)
        hipLaunchKernelGGL(k_pool2, dim3(NB, NSLICE), dim3(256), 0, stream,
                           xoutb, batch, psum_p, pmax_p, cnt);
        hipLaunchKernelGGL(k_poolfin, dim3((NB * 1024 + 255) / 256), dim3(256), 0, stream,
                           psum_p, pmax_p, cnt, hsum, poolmode);
    };

    // layer 1: x_b (N,128) -> x1_b ; layer 2: x1_b (N,512) -> x1_b
    run_layer(x_b, IN_CH, wcat1, bcat, w_e, x1_b, /*poolmode=*/0);
    run_layer(x1_b, HC, wcat2, bcat + NCAT, w_e + (size_t)HC * EDP, x1_b, /*poolmode=*/1);

    hipLaunchKernelGGL(k_head, dim3(NB), dim3(256), 0, stream,
                       hsum, fc1_W, fc1_b, fc2_W, fc2_b, (float*)d_out);
}

// Round 30
// 514.853 us; speedup vs baseline: 1.1402x; 1.0496x over previous
//
#include <hip/hip_runtime.h>
#include <cstdint>
#include <cstddef>

#define N_NODES 20000
#define N_EDGES 160000
#define IN_CH   128
#define NH      16
#define CD      32
#define HC      512   // NH*CD
#define ED      93
#define EDP     96    // ED padded to multiple of 32
#define NB      64
#define NCAT    2048  // q|k|v|skip GEMM output cols (all bf16)
#define NSLICE  8
#define ECSLK   2048  // edge-count slack per node-chunk (>=7 sigma of binomial split)

typedef __attribute__((ext_vector_type(8))) short short8;
typedef __attribute__((ext_vector_type(4))) float f32x4;
typedef __attribute__((ext_vector_type(4))) unsigned int u32x4;
typedef unsigned short ushort_t;

// ---------------------------------------------------------------- utilities

__device__ inline ushort_t f2bf(float f) {
    unsigned int u = __float_as_uint(f);
    u = (u + 0x7FFF + ((u >> 16) & 1)) >> 16;   // RNE
    return (ushort_t)u;
}
__device__ inline float bf2f(ushort_t u) {
    return __uint_as_float((unsigned)u << 16);
}
__device__ inline void unpack8(uint4 u, float* o) {
    o[0] = bf2f((ushort_t)(u.x & 0xffff)); o[1] = bf2f((ushort_t)(u.x >> 16));
    o[2] = bf2f((ushort_t)(u.y & 0xffff)); o[3] = bf2f((ushort_t)(u.y >> 16));
    o[4] = bf2f((ushort_t)(u.z & 0xffff)); o[5] = bf2f((ushort_t)(u.z >> 16));
    o[6] = bf2f((ushort_t)(u.w & 0xffff)); o[7] = bf2f((ushort_t)(u.w >> 16));
}
__device__ inline uint4 packf8(const float* f) {
    uint4 u;
    u.x = (unsigned)f2bf(f[0]) | ((unsigned)f2bf(f[1]) << 16);
    u.y = (unsigned)f2bf(f[2]) | ((unsigned)f2bf(f[3]) << 16);
    u.z = (unsigned)f2bf(f[4]) | ((unsigned)f2bf(f[5]) << 16);
    u.w = (unsigned)f2bf(f[6]) | ((unsigned)f2bf(f[7]) << 16);
    return u;
}

// non-temporal 16B load/store shims (builtin needs native vector types)
__device__ inline uint4 ntload16(const void* p) {
    u32x4 v = __builtin_nontemporal_load((const u32x4*)p);
    uint4 r; r.x = v.x; r.y = v.y; r.z = v.z; r.w = v.w; return r;
}
__device__ inline void ntstore16(void* p, uint4 v) {
    u32x4 t; t.x = v.x; t.y = v.y; t.z = v.z; t.w = v.w;
    __builtin_nontemporal_store(t, (u32x4*)p);
}

// async global->LDS, 16B per lane; lds dest = wave-uniform base + lane*16
__device__ inline void gload_lds16(const void* g, void* l) {
    __builtin_amdgcn_global_load_lds(
        (const __attribute__((address_space(1))) void*)g,
        (__attribute__((address_space(3))) void*)l, 16, 0, 0);
}

__global__ void k_zero_i(int* __restrict__ p, int n) {
    int i = blockIdx.x * blockDim.x + threadIdx.x;
    int stride = gridDim.x * blockDim.x;
    for (; i < n; i += stride) p[i] = 0;
}

// x f32 -> bf16, 8 elems/thread vectorized (n % 8 == 0)
__global__ void k_cvt_x(const float* __restrict__ in, ushort_t* __restrict__ out, int n8) {
    int i = blockIdx.x * blockDim.x + threadIdx.x;
    int stride = gridDim.x * blockDim.x;
    for (; i < n8; i += stride) {
        const float4* p = (const float4*)(in + (size_t)i * 8);
        float4 a = p[0], b = p[1];
        float f[8] = {a.x, a.y, a.z, a.w, b.x, b.y, b.z, b.w};
        *(uint4*)(out + (size_t)i * 8) = packf8(f);
    }
}

// edge_attr [E,93] f32 -> PERMUTED [E,96] bf16: out row p = in row perm[p].
__global__ void k_cvt_ea(const float* __restrict__ in, const int* __restrict__ perm,
                         ushort_t* __restrict__ out) {
    int i = blockIdx.x * blockDim.x + threadIdx.x;
    int stride = gridDim.x * blockDim.x;
    int total = N_EDGES * EDP;
    for (; i < total; i += stride) {
        int p = i / EDP, k = i - p * EDP;
        int e = perm[p];
        out[i] = (k < ED) ? f2bf(in[(size_t)e * ED + k]) : (ushort_t)0;
    }
}

// LDS-tiled transposed weight conversion
__global__ __launch_bounds__(256) void k_cvt_wtT(
    const float* __restrict__ W0, const float* __restrict__ W1,
    const float* __restrict__ W2, const float* __restrict__ W3,
    ushort_t* __restrict__ Wt, int K, int N, int Kp) {
    __shared__ float tile[32][33];
    int z = blockIdx.z;
    const float* W = (z == 0) ? W0 : (z == 1) ? W1 : (z == 2) ? W2 : W3;
    ushort_t* out = Wt + (size_t)z * N * Kp;
    int n0 = blockIdx.x << 5;
    int k0 = blockIdx.y << 5;
    int r = threadIdx.x >> 5;   // 0..7
    int c = threadIdx.x & 31;
#pragma unroll
    for (int rr = 0; rr < 4; ++rr) {
        int k = k0 + r + rr * 8;
        tile[r + rr * 8][c] = (k < K) ? W[(size_t)k * N + n0 + c] : 0.f;
    }
    __syncthreads();
#pragma unroll
    for (int rr = 0; rr < 4; ++rr) {
        int n = n0 + r + rr * 8;
        out[(size_t)n * Kp + k0 + c] = f2bf(tile[c][r + rr * 8]);
    }
}

// bcat[2][2048] = (bq|bk|bv|bs) per layer, one dispatch
__global__ void k_bcat2(
    const float* __restrict__ b0q, const float* __restrict__ b0k,
    const float* __restrict__ b0v, const float* __restrict__ b0s,
    const float* __restrict__ b1q, const float* __restrict__ b1k,
    const float* __restrict__ b1v, const float* __restrict__ b1s,
    float* __restrict__ out) {
    int i = blockIdx.x * blockDim.x + threadIdx.x;
    if (i >= 2 * NCAT) return;
    int l = i >> 11, j = i & (NCAT - 1);
    int s = j >> 9, jj = j & 511;
    const float* b = (l == 0)
        ? ((s == 0) ? b0q : (s == 1) ? b0k : (s == 2) ? b0v : b0s)
        : ((s == 0) ? b1q : (s == 1) ? b1k : (s == 2) ? b1v : b1s);
    out[i] = b[jj];
}

// ---------------------------------------------------------------- CSR build

__global__ void k_hist(const int* __restrict__ dst, int* __restrict__ deg) {
    int i = blockIdx.x * blockDim.x + threadIdx.x;
    if (i < N_EDGES) atomicAdd(&deg[dst[i]], 1);
}

__global__ __launch_bounds__(1024) void k_scan(const int* __restrict__ deg,
                                               int* __restrict__ rowptr,
                                               int* __restrict__ cursor) {
    __shared__ int part[1024];
    int t = threadIdx.x;
    int base = t * 20;
    int loc[20];
    int s = 0;
#pragma unroll
    for (int i = 0; i < 20; ++i) {
        int idx = base + i;
        int v = (idx < N_NODES) ? deg[idx] : 0;
        loc[i] = s; s += v;
    }
    part[t] = s;
    __syncthreads();
    for (int off = 1; off < 1024; off <<= 1) {
        int v = (t >= off) ? part[t - off] : 0;
        __syncthreads();
        part[t] += v;
        __syncthreads();
    }
    int pre = (t > 0) ? part[t - 1] : 0;
#pragma unroll
    for (int i = 0; i < 20; ++i) {
        int idx = base + i;
        if (idx < N_NODES) {
            int v = pre + loc[i];
            rowptr[idx] = v;
            cursor[idx] = v;
        }
    }
    if (t == 1023) rowptr[N_NODES] = part[1023];
}

__global__ void k_scatter(const int* __restrict__ src, const int* __restrict__ dst,
                          int* __restrict__ cursor, int* __restrict__ perm,
                          int* __restrict__ psrc) {
    int i = blockIdx.x * blockDim.x + threadIdx.x;
    if (i >= N_EDGES) return;
    int d = dst[i];
    int p = atomicAdd(&cursor[d], 1);
    perm[p] = i;
    psrc[p] = src[i];
}

// ---------------------------------------------------------------- MEGA kernel
// blocks [0,nq): QKVS GEMM; blocks [nq,nq+neg): edge-GEMM for nodes [0,n1):
// edges [0, rowptr[n1]) (device-read bound). Bodies inline verbatim.

__global__ __launch_bounds__(256) void k_mega(
    const ushort_t* __restrict__ A, const ushort_t* __restrict__ Bt,
    const float* __restrict__ bias, ushort_t* __restrict__ Yb,
    int M, int K, int N, int nq,
    const ushort_t* __restrict__ Ab, const ushort_t* __restrict__ Bte,
    ushort_t* __restrict__ Ybe, const int* __restrict__ rowptrd, int n1, int neg) {
    __shared__ char smem[49152];
    int tid  = threadIdx.x;
    int lane = tid & 63, wave = tid >> 6;
    int l15 = lane & 15, lg = lane >> 4;
    int wm = (wave >> 1) * 64, wn = (wave & 1) * 64;

    if ((int)blockIdx.x < nq) {
        // ---------------- QKVS body ----------------
        char* As = smem;
        char* Bs = smem + 16384;
        int nt = N >> 7;
        int bid = blockIdx.x;
        int wg;
        if ((nq & 7) == 0) { int cpx = nq >> 3; wg = (bid & 7) * cpx + (bid >> 3); }
        else wg = bid;
        int bm = (wg / nt) * 128, bn = (wg % nt) * 128;

        f32x4 acc[4][4] = {};

        int sr = lane >> 3;
        int su = lane & 7;
        int gu = su ^ sr;

        for (int k0 = 0; k0 < K; k0 += 64) {
#pragma unroll
            for (int i = 0; i < 4; ++i) {
                int rloc = wave * 32 + i * 8;
                int row = rloc + sr;
                if (bm + row < M)
                    gload_lds16(A + (size_t)(bm + row) * K + k0 + gu * 8, As + rloc * 128);
                gload_lds16(Bt + (size_t)(bn + row) * K + k0 + gu * 8, Bs + rloc * 128);
            }
            __syncthreads();

#pragma unroll
            for (int ks = 0; ks < 2; ++ks) {
                short8 af[4], bfr[4];
#pragma unroll
                for (int mr = 0; mr < 4; ++mr) {
                    int r = wm + mr * 16 + l15;
                    af[mr] = *(const short8*)(As + r * 128 + (((ks * 4 + lg) ^ (r & 7)) << 4));
                }
#pragma unroll
                for (int nc = 0; nc < 4; ++nc) {
                    int r = wn + nc * 16 + l15;
                    bfr[nc] = *(const short8*)(Bs + r * 128 + (((ks * 4 + lg) ^ (r & 7)) << 4));
                }
#pragma unroll
                for (int mr = 0; mr < 4; ++mr)
#pragma unroll
                    for (int nc = 0; nc < 4; ++nc)
                        acc[mr][nc] = __builtin_amdgcn_mfma_f32_16x16x32_bf16(
                            af[mr], bfr[nc], acc[mr][nc], 0, 0, 0);
            }
            __syncthreads();
        }

        char* Cs = smem;
#pragma unroll
        for (int mr = 0; mr < 4; ++mr) {
#pragma unroll
            for (int nc = 0; nc < 4; ++nc) {
                int coll = wn + nc * 16 + l15;
                float b = bias ? bias[bn + coll] : 0.f;
                int u0 = coll >> 3;
#pragma unroll
                for (int j = 0; j < 4; ++j) {
                    int row = wm + mr * 16 + lg * 4 + j;
                    int u = u0 ^ (row & 7);
                    *(ushort_t*)(Cs + row * 256 + (u << 4) + ((coll & 7) << 1)) =
                        f2bf(acc[mr][nc][j] + b);
                }
            }
        }
        __syncthreads();
        {
            int rsub = tid >> 4;
            int un   = tid & 15;
#pragma unroll
            for (int i = 0; i < 8; ++i) {
                int row = i * 16 + rsub;
                int gr = bm + row;
                if (gr < M) {
                    int u = un ^ (row & 7);
                    *(uint4*)(Yb + (size_t)gr * N + bn + un * 8) =
                        *(const uint4*)(Cs + row * 256 + (u << 4));
                }
            }
        }
    } else {
        // ---------------- edge-GEMM body (chunk 0: pbase = 0, ec from rowptr) ----------------
        int ec = rowptrd[n1];
        char* As = smem;
        char* Bs = smem + 24576;
        int bid = blockIdx.x - nq;
        int wg;
        if ((neg & 7) == 0) { int cpx = neg >> 3; wg = (bid & 7) * cpx + (bid >> 3); }
        else wg = bid;
        int bm = (wg >> 2) * 128;
        int n0 = (wg & 3) * 128;

        int srow = tid >> 1;
        int h    = tid & 1;
        int ssw  = ((srow >> 1) & 3) << 4;
        {
            int gm = bm + srow;
            uint4 va[6];
#pragma unroll
            for (int i = 0; i < 6; ++i) { va[i].x = va[i].y = va[i].z = va[i].w = 0; }
            if (gm < ec) {
                const uint4* ga = (const uint4*)(Ab + (size_t)gm * EDP + h * 48);
#pragma unroll
                for (int i = 0; i < 6; ++i) va[i] = ga[i];
            }
            char* dsta = As + srow * 192;
#pragma unroll
            for (int i = 0; i < 6; ++i) {
                int c = h * 96 + i * 16;
                *(uint4*)(dsta + ((c & ~63) | ((c & 63) ^ ssw))) = va[i];
            }
            uint4 vb[6];
            {
                const uint4* gb = (const uint4*)(Bte + (size_t)(n0 + srow) * EDP + h * 48);
#pragma unroll
                for (int i = 0; i < 6; ++i) vb[i] = gb[i];
            }
            char* dstb = Bs + srow * 192;
#pragma unroll
            for (int i = 0; i < 6; ++i) {
                int c = h * 96 + i * 16;
                *(uint4*)(dstb + ((c & ~63) | ((c & 63) ^ ssw))) = vb[i];
            }
        }
        __syncthreads();

        int fsw = ((l15 >> 1) & 3) << 4;

        f32x4 acc[4][4] = {};
#pragma unroll
        for (int ks = 0; ks < 3; ++ks) {
            short8 af[4], bfr[4];
#pragma unroll
            for (int mr = 0; mr < 4; ++mr) {
                int r = wm + mr * 16 + l15;
                int c = ks * 64 + ((lg * 16) ^ fsw);
                af[mr] = *(const short8*)(As + r * 192 + c);
            }
#pragma unroll
            for (int nc = 0; nc < 4; ++nc) {
                int r = wn + nc * 16 + l15;
                int c = ks * 64 + ((lg * 16) ^ fsw);
                bfr[nc] = *(const short8*)(Bs + r * 192 + c);
            }
#pragma unroll
            for (int mr = 0; mr < 4; ++mr)
#pragma unroll
                for (int nc = 0; nc < 4; ++nc)
                    acc[mr][nc] = __builtin_amdgcn_mfma_f32_16x16x32_bf16(
                        af[mr], bfr[nc], acc[mr][nc], 0, 0, 0);
        }
        __syncthreads();

        char* Cs = smem;   // 128 rows * 288B stride = 36864
#pragma unroll
        for (int mr = 0; mr < 4; ++mr) {
#pragma unroll
            for (int nc = 0; nc < 4; ++nc) {
                int col = wn + nc * 16 + l15;
#pragma unroll
                for (int j = 0; j < 4; ++j) {
                    int row = wm + mr * 16 + lg * 4 + j;
                    *(ushort_t*)(Cs + row * 288 + col * 2) = f2bf(acc[mr][nc][j]);
                }
            }
        }
        __syncthreads();

        {
            int rsub = tid >> 4;
            int un   = tid & 15;
#pragma unroll
            for (int i = 0; i < 8; ++i) {
                int row = i * 16 + rsub;
                if (bm + row < ec) {
                    ntstore16(Ybe + (size_t)(bm + row) * HC + n0 + un * 8,
                              *(const uint4*)(Cs + row * 288 + un * 16));
                }
            }
        }
    }
}

// ---------------------------------------------------------------- standalone QKVS
// (kept only for codegen isolation; not launched in normal path)

__global__ __launch_bounds__(256) void k_mfma_gemm(
    const ushort_t* __restrict__ A, const ushort_t* __restrict__ Bt,
    const float* __restrict__ bias, ushort_t* __restrict__ Yb,
    int M, int K, int N) {
    __shared__ char smem[32768];
    char* As = smem;
    char* Bs = smem + 16384;

    int tid  = threadIdx.x;
    int lane = tid & 63, wave = tid >> 6;
    int l15 = lane & 15, lg = lane >> 4;
    int nt = N >> 7;
    int nwg = gridDim.x;
    int bid = blockIdx.x;
    int wg;
    if ((nwg & 7) == 0) { int cpx = nwg >> 3; wg = (bid & 7) * cpx + (bid >> 3); }
    else wg = bid;
    int bm = (wg / nt) * 128, bn = (wg % nt) * 128;
    int wm = (wave >> 1) * 64, wn = (wave & 1) * 64;

    f32x4 acc[4][4] = {};

    int sr = lane >> 3;
    int su = lane & 7;
    int gu = su ^ sr;

    for (int k0 = 0; k0 < K; k0 += 64) {
#pragma unroll
        for (int i = 0; i < 4; ++i) {
            int rloc = wave * 32 + i * 8;
            int row = rloc + sr;
            if (bm + row < M)
                gload_lds16(A + (size_t)(bm + row) * K + k0 + gu * 8, As + rloc * 128);
            gload_lds16(Bt + (size_t)(bn + row) * K + k0 + gu * 8, Bs + rloc * 128);
        }
        __syncthreads();

#pragma unroll
        for (int ks = 0; ks < 2; ++ks) {
            short8 af[4], bfr[4];
#pragma unroll
            for (int mr = 0; mr < 4; ++mr) {
                int r = wm + mr * 16 + l15;
                af[mr] = *(const short8*)(As + r * 128 + (((ks * 4 + lg) ^ (r & 7)) << 4));
            }
#pragma unroll
            for (int nc = 0; nc < 4; ++nc) {
                int r = wn + nc * 16 + l15;
                bfr[nc] = *(const short8*)(Bs + r * 128 + (((ks * 4 + lg) ^ (r & 7)) << 4));
            }
#pragma unroll
            for (int mr = 0; mr < 4; ++mr)
#pragma unroll
                for (int nc = 0; nc < 4; ++nc)
                    acc[mr][nc] = __builtin_amdgcn_mfma_f32_16x16x32_bf16(
                        af[mr], bfr[nc], acc[mr][nc], 0, 0, 0);
        }
        __syncthreads();
    }

    char* Cs = smem;
#pragma unroll
    for (int mr = 0; mr < 4; ++mr) {
#pragma unroll
        for (int nc = 0; nc < 4; ++nc) {
            int coll = wn + nc * 16 + l15;
            float b = bias ? bias[bn + coll] : 0.f;
            int u0 = coll >> 3;
#pragma unroll
            for (int j = 0; j < 4; ++j) {
                int row = wm + mr * 16 + lg * 4 + j;
                int u = u0 ^ (row & 7);
                *(ushort_t*)(Cs + row * 256 + (u << 4) + ((coll & 7) << 1)) =
                    f2bf(acc[mr][nc][j] + b);
            }
        }
    }
    __syncthreads();
    {
        int rsub = tid >> 4;
        int un   = tid & 15;
#pragma unroll
        for (int i = 0; i < 8; ++i) {
            int row = i * 16 + rsub;
            int gr = bm + row;
            if (gr < M) {
                int u = un ^ (row & 7);
                *(uint4*)(Yb + (size_t)gr * N + bn + un * 8) =
                    *(const uint4*)(Cs + row * 256 + (u << 4));
            }
        }
    }
}

// ---------------------------------------------------------------- edge GEMM
// eb[r-pbase, :512] = ea_b[r, :96] @ We[512,96]^T for r in [rowptr[nlo], rowptr[nhi]).

__global__ __launch_bounds__(256) void k_egemm(
    const ushort_t* __restrict__ Ab, const ushort_t* __restrict__ Bt,
    ushort_t* __restrict__ Yb, const int* __restrict__ rowptrd,
    int nlo, int nhi) {
    __shared__ char smem[49152];
    char* As = smem;
    char* Bs = smem + 24576;

    int pbase = rowptrd[nlo];
    int ec    = rowptrd[nhi] - pbase;

    int tid  = threadIdx.x;
    int lane = tid & 63, wave = tid >> 6;
    int l15 = lane & 15, lg = lane >> 4;
    int nwg = gridDim.x;
    int bid = blockIdx.x;
    int wg;
    if ((nwg & 7) == 0) { int cpx = nwg >> 3; wg = (bid & 7) * cpx + (bid >> 3); }
    else wg = bid;
    int bm = (wg >> 2) * 128;
    int n0 = (wg & 3) * 128;
    int wm = (wave >> 1) * 64, wn = (wave & 1) * 64;

    int srow = tid >> 1;
    int h    = tid & 1;
    int ssw  = ((srow >> 1) & 3) << 4;
    {
        int gm = bm + srow;
        uint4 va[6];
#pragma unroll
        for (int i = 0; i < 6; ++i) { va[i].x = va[i].y = va[i].z = va[i].w = 0; }
        if (gm < ec) {
            const uint4* ga = (const uint4*)(Ab + (size_t)(pbase + gm) * EDP + h * 48);
#pragma unroll
            for (int i = 0; i < 6; ++i) va[i] = ga[i];
        }
        char* dsta = As + srow * 192;
#pragma unroll
        for (int i = 0; i < 6; ++i) {
            int c = h * 96 + i * 16;
            *(uint4*)(dsta + ((c & ~63) | ((c & 63) ^ ssw))) = va[i];
        }
        uint4 vb[6];
        {
            const uint4* gb = (const uint4*)(Bt + (size_t)(n0 + srow) * EDP + h * 48);
#pragma unroll
            for (int i = 0; i < 6; ++i) vb[i] = gb[i];
        }
        char* dstb = Bs + srow * 192;
#pragma unroll
        for (int i = 0; i < 6; ++i) {
            int c = h * 96 + i * 16;
            *(uint4*)(dstb + ((c & ~63) | ((c & 63) ^ ssw))) = vb[i];
        }
    }
    __syncthreads();

    int fsw = ((l15 >> 1) & 3) << 4;

    f32x4 acc[4][4] = {};
#pragma unroll
    for (int ks = 0; ks < 3; ++ks) {
        short8 af[4], bfr[4];
#pragma unroll
        for (int mr = 0; mr < 4; ++mr) {
            int r = wm + mr * 16 + l15;
            int c = ks * 64 + ((lg * 16) ^ fsw);
            af[mr] = *(const short8*)(As + r * 192 + c);
        }
#pragma unroll
        for (int nc = 0; nc < 4; ++nc) {
            int r = wn + nc * 16 + l15;
            int c = ks * 64 + ((lg * 16) ^ fsw);
            bfr[nc] = *(const short8*)(Bs + r * 192 + c);
        }
#pragma unroll
        for (int mr = 0; mr < 4; ++mr)
#pragma unroll
            for (int nc = 0; nc < 4; ++nc)
                acc[mr][nc] = __builtin_amdgcn_mfma_f32_16x16x32_bf16(
                    af[mr], bfr[nc], acc[mr][nc], 0, 0, 0);
    }
    __syncthreads();

    char* Cs = smem;   // 128 rows * 288B stride = 36864
#pragma unroll
    for (int mr = 0; mr < 4; ++mr) {
#pragma unroll
        for (int nc = 0; nc < 4; ++nc) {
            int col = wn + nc * 16 + l15;
#pragma unroll
            for (int j = 0; j < 4; ++j) {
                int row = wm + mr * 16 + lg * 4 + j;
                *(ushort_t*)(Cs + row * 288 + col * 2) = f2bf(acc[mr][nc][j]);
            }
        }
    }
    __syncthreads();

    {
        int rsub = tid >> 4;
        int un   = tid & 15;
#pragma unroll
        for (int i = 0; i < 8; ++i) {
            int row = i * 16 + rsub;
            if (bm + row < ec) {
                ntstore16(Yb + (size_t)(bm + row) * HC + n0 + un * 8,
                          *(const uint4*)(Cs + row * 288 + un * 16));
            }
        }
    }
}

// ---------------------------------------------------------------- fused edge phase
// NODE-RANGE variant: block b handles node n = nlo + b (grid = nhi-nlo exactly).
// Depth-2 software pipeline; eb reads non-temporal (preserve L2 for k/v gathers).

__global__ __launch_bounds__(128) void k_edge_fc(
    const ushort_t* __restrict__ qkvs, const ushort_t* __restrict__ eb,
    const int* __restrict__ psrc, const int* __restrict__ rowptrd,
    ushort_t* __restrict__ xoutb, int nlo) {
    int n = nlo + blockIdx.x;
    int e0 = rowptrd[nlo];
    int beg = rowptrd[n], end = rowptrd[n + 1];

    int t = threadIdx.x;
    int w = t >> 6;
    int lane = t & 63;
    int c0 = lane * 8;
    int h = lane >> 2;

    // 3-slot pipeline: slots A (edge i) and B (edge i+2) in flight before q load
    uint4 ka = {}, va = {}, ea = {}, kb = {}, vb = {}, eb4 = {};
    int i = beg + w;
    if (i < end) {
        int sn = psrc[i];
        ka = *(const uint4*)(qkvs + (size_t)sn * NCAT + 512 + c0);
        va = *(const uint4*)(qkvs + (size_t)sn * NCAT + 1024 + c0);
        ea = ntload16(eb + (size_t)(i - e0) * HC + c0);
    }
    if (i + 2 < end) {
        int sn = psrc[i + 2];
        kb = *(const uint4*)(qkvs + (size_t)sn * NCAT + 512 + c0);
        vb = *(const uint4*)(qkvs + (size_t)sn * NCAT + 1024 + c0);
        eb4 = ntload16(eb + (size_t)(i + 2 - e0) * HC + c0);
    }

    float q[8];
    unpack8(*(const uint4*)(qkvs + (size_t)n * NCAT + c0), q);

    float mm = -1e30f, dd = 0.f, a[8];
#pragma unroll
    for (int j = 0; j < 8; ++j) a[j] = 0.f;

    while (i < end) {
        uint4 kc = ka, vc = va, ec = ea;
        ka = kb; va = vb; ea = eb4;
        int inx = i + 4;
        if (inx < end) {
            int sn2 = psrc[inx];
            kb = *(const uint4*)(qkvs + (size_t)sn2 * NCAT + 512 + c0);
            vb = *(const uint4*)(qkvs + (size_t)sn2 * NCAT + 1024 + c0);
            eb4 = ntload16(eb + (size_t)(inx - e0) * HC + c0);
        }
        float kk[8], vv[8], ee[8];
        unpack8(kc, kk); unpack8(vc, vv); unpack8(ec, ee);
        float part = 0.f;
#pragma unroll
        for (int j = 0; j < 8; ++j) part += q[j] * (kk[j] + ee[j]);
        part += __shfl_xor(part, 1);
        part += __shfl_xor(part, 2);
        float s = part * 0.17677669529663687f;   // /sqrt(32)
        float mn = fmaxf(mm, s);
        float sc = __expf(mm - mn);
        float p  = __expf(s - mn);
        dd = dd * sc + p;
        mm = mn;
#pragma unroll
        for (int j = 0; j < 8; ++j) a[j] = a[j] * sc + p * (vv[j] + ee[j]);
        i += 2;
    }

    __shared__ float sm_acc[512];
    __shared__ float sm_m[16];
    __shared__ float sm_d[16];
    if (w == 1) {
#pragma unroll
        for (int j = 0; j < 8; ++j) sm_acc[c0 + j] = a[j];
        if ((lane & 3) == 0) { sm_m[h] = mm; sm_d[h] = dd; }
    }
    __syncthreads();
    if (w == 0) {
        float m1 = sm_m[h], d1 = sm_d[h];
        float M = fmaxf(mm, m1);
        float sc0 = __expf(mm - M);
        float sc1 = __expf(m1 - M);
        dd = dd * sc0 + d1 * sc1;
        float inv = (dd > 0.f) ? 1.f / dd : 0.f;
        float sk[8];
        unpack8(*(const uint4*)(qkvs + (size_t)n * NCAT + 1536 + c0), sk);
        float o[8];
#pragma unroll
        for (int j = 0; j < 8; ++j) {
            float msg = (a[j] * sc0 + sm_acc[c0 + j] * sc1) * inv;
            float v = msg + sk[j];
            o[j] = v >= 0.f ? v : 0.2f * v;
        }
        *(uint4*)(xoutb + (size_t)n * HC + c0) = packf8(o);
    }
}

// ---------------------------------------------------------------- pooling (bf16 in)

__global__ __launch_bounds__(256) void k_pool2(
    const ushort_t* __restrict__ xb, const int* __restrict__ batch,
    float* __restrict__ psum_p, float* __restrict__ pmax_p, int* __restrict__ cnt) {
    int b = blockIdx.x;
    int s = blockIdx.y;
    int lo = 0, hi = N_NODES;
    while (lo < hi) { int mid = (lo + hi) >> 1; if (batch[mid] < b) lo = mid + 1; else hi = mid; }
    int beg = lo;
    hi = N_NODES;
    while (lo < hi) { int mid = (lo + hi) >> 1; if (batch[mid] < b + 1) lo = mid + 1; else hi = mid; }
    int end = lo;
    if (s == 0 && threadIdx.x == 0) cnt[b] = end - beg;
    int cn = end - beg;
    int per = (cn + NSLICE - 1) / NSLICE;
    int nb = beg + s * per;
    int ne = nb + per; if (ne > end) ne = end;
    int c0 = threadIdx.x * 2;
    float s0 = 0.f, s1 = 0.f, m0 = -1e30f, m1 = -1e30f;
    for (int n = nb; n < ne; ++n) {
        unsigned int v = *(const unsigned int*)(xb + (size_t)n * HC + c0);
        float v0 = bf2f((ushort_t)(v & 0xffff));
        float v1 = bf2f((ushort_t)(v >> 16));
        s0 += v0; s1 += v1;
        m0 = fmaxf(m0, v0); m1 = fmaxf(m1, v1);
    }
    size_t o = ((size_t)s * NB + b) * HC + c0;
    psum_p[o] = s0; psum_p[o + 1] = s1;
    pmax_p[o] = m0; pmax_p[o + 1] = m1;
}

__global__ void k_poolfin(const float* __restrict__ psum_p, const float* __restrict__ pmax_p,
                          const int* __restrict__ cnt, float* __restrict__ hsum, int mode) {
    int i = blockIdx.x * blockDim.x + threadIdx.x;
    if (i >= NB * 1024) return;
    int b = i >> 10, c = i & 1023;
    float val;
    if (c < HC) {
        float s = 0.f;
#pragma unroll
        for (int sl = 0; sl < NSLICE; ++sl)
            s += psum_p[((size_t)sl * NB + b) * HC + c];
        int ct = cnt[b];
        val = s / (float)(ct > 0 ? ct : 1);
    } else {
        int cc = c - HC;
        float m = -1e30f;
#pragma unroll
        for (int sl = 0; sl < NSLICE; ++sl)
            m = fmaxf(m, pmax_p[((size_t)sl * NB + b) * HC + cc]);
        val = m;
    }
    if (mode == 0) hsum[i] = val;
    else hsum[i] += val;
}

// ---------------------------------------------------------------- MLP head

__global__ __launch_bounds__(256) void k_head(
    const float* __restrict__ hsum, const float* __restrict__ fc1W,
    const float* __restrict__ fc1b, const float* __restrict__ fc2W,
    const float* __restrict__ fc2b, float* __restrict__ out) {
    int b = blockIdx.x;
    int j = threadIdx.x;
    __shared__ float hs[256];
    float acc = fc1b[j];
    const float* hin = hsum + (size_t)b * 1024;
    for (int k = 0; k < 1024; ++k) {
        acc += hin[k] * fc1W[(size_t)k * 256 + j];
    }
    hs[j] = fmaxf(acc, 0.f);
    __syncthreads();
    if (j < 32) {
        float o = fc2b[j];
        for (int k = 0; k < 256; ++k) o += hs[k] * fc2W[(size_t)k * 32 + j];
        out[b * 32 + j] = o;
    }
}

// ---------------------------------------------------------------- driver

extern "C" void kernel_launch(void* const* d_in, const int* in_sizes, int n_in,
                              void* d_out, int out_size, void* d_ws, size_t ws_size,
                              hipStream_t stream) {
    const float* x      = (const float*)d_in[0];
    const float* ea     = (const float*)d_in[1];
    const int*   ei     = (const int*)d_in[2];
    const int*   batch  = (const int*)d_in[3];
    const int* src = ei;
    const int* dst = ei + N_EDGES;

    const float* t1_Wq = (const float*)d_in[4];
    const float* t1_bq = (const float*)d_in[5];
    const float* t1_Wk = (const float*)d_in[6];
    const float* t1_bk = (const float*)d_in[7];
    const float* t1_Wv = (const float*)d_in[8];
    const float* t1_bv = (const float*)d_in[9];
    const float* t1_We = (const float*)d_in[10];
    const float* t1_Ws = (const float*)d_in[11];
    const float* t1_bs = (const float*)d_in[12];
    const float* t2_Wq = (const float*)d_in[13];
    const float* t2_bq = (const float*)d_in[14];
    const float* t2_Wk = (const float*)d_in[15];
    const float* t2_bk = (const float*)d_in[16];
    const float* t2_Wv = (const float*)d_in[17];
    const float* t2_bv = (const float*)d_in[18];
    const float* t2_We = (const float*)d_in[19];
    const float* t2_Ws = (const float*)d_in[20];
    const float* t2_bs = (const float*)d_in[21];
    const float* fc1_W = (const float*)d_in[22];
    const float* fc1_b = (const float*)d_in[23];
    const float* fc2_W = (const float*)d_in[24];
    const float* fc2_b = (const float*)d_in[25];

    char* ws = (char*)d_ws;
    size_t off = 0;
    auto alloc = [&](size_t bytes) -> void* {
        void* p = ws + off;
        off = (off + bytes + 255) & ~(size_t)255;
        return p;
    };

    // ---- fixed buffers ----
    ushort_t* qkvs = (ushort_t*)alloc((size_t)N_NODES * NCAT * 2);  // q|k|v|skip bf16
    float* psum_p = (float*)alloc((size_t)NSLICE * NB * HC * 4);
    float* pmax_p = (float*)alloc((size_t)NSLICE * NB * HC * 4);
    float* hsum = (float*)alloc((size_t)NB * 1024 * 4);
    int*   cnt  = (int*)alloc((size_t)NB * 4);
    int* deg    = (int*)alloc((size_t)N_NODES * 4);
    int* rowptr = (int*)alloc((size_t)(N_NODES + 1) * 4);
    int* cursor = (int*)alloc((size_t)N_NODES * 4);
    int* perm   = (int*)alloc((size_t)N_EDGES * 4);
    int* psrc   = (int*)alloc((size_t)N_EDGES * 4);
    ushort_t* x_b  = (ushort_t*)alloc((size_t)N_NODES * IN_CH * 2);
    ushort_t* x1_b = (ushort_t*)alloc((size_t)N_NODES * HC * 2);
    ushort_t* ea_b = (ushort_t*)alloc((size_t)N_EDGES * EDP * 2);   // dst-sorted
    ushort_t* wcat1 = (ushort_t*)alloc((size_t)NCAT * IN_CH * 2);
    ushort_t* wcat2 = (ushort_t*)alloc((size_t)NCAT * HC * 2);
    ushort_t* w_e   = (ushort_t*)alloc((size_t)2 * HC * EDP * 2);  // [2][HC][EDP]
    float* bcat = (float*)alloc((size_t)2 * NCAT * 4);             // [2][NCAT]

    // ---- eb: node-range chunk window, sized from remaining workspace ----
    size_t remain = (ws_size > off) ? (ws_size - off) : 0;
    ushort_t* eb = (ushort_t*)(ws + off);
    size_t per_edge = (size_t)HC * 2;                // 1 KiB per edge row
    long cap_rows = (long)(remain / per_edge);
    int nchN = 1;
    long ecap = N_EDGES;
    if (cap_rows < (long)N_EDGES) {
        nchN = -1;
        for (int c = 2; c <= 64; ++c) {
            long e = (long)(N_EDGES + c - 1) / c + ECSLK;
            if (e <= cap_rows) { nchN = c; ecap = e; break; }
        }
        if (nchN < 0) { nchN = 64; ecap = cap_rows > 1024 ? cap_rows : 1024; }
    }
    int Nc = (N_NODES + nchN - 1) / nchN;            // nodes per chunk
    (void)in_sizes; (void)n_in; (void)out_size;

    // ---- CSR build (before ea conversion: k_cvt_ea uses perm)
    hipLaunchKernelGGL(k_zero_i, dim3(79), dim3(256), 0, stream, deg, N_NODES);
    hipLaunchKernelGGL(k_hist, dim3((N_EDGES + 255) / 256), dim3(256), 0, stream, dst, deg);
    hipLaunchKernelGGL(k_scan, dim3(1), dim3(1024), 0, stream, deg, rowptr, cursor);
    hipLaunchKernelGGL(k_scatter, dim3((N_EDGES + 255) / 256), dim3(256), 0, stream,
                       src, dst, cursor, perm, psrc);

    // ---- conversions
    hipLaunchKernelGGL(k_cvt_x, dim3(512), dim3(256), 0, stream, x, x_b,
                       N_NODES * IN_CH / 8);
    hipLaunchKernelGGL(k_cvt_ea, dim3(4096), dim3(256), 0, stream, ea, perm, ea_b);
    hipLaunchKernelGGL(k_cvt_wtT, dim3(HC / 32, IN_CH / 32, 4), dim3(256), 0, stream,
                       t1_Wq, t1_Wk, t1_Wv, t1_Ws, wcat1, IN_CH, HC, IN_CH);
    hipLaunchKernelGGL(k_cvt_wtT, dim3(HC / 32, HC / 32, 4), dim3(256), 0, stream,
                       t2_Wq, t2_Wk, t2_Wv, t2_Ws, wcat2, HC, HC, HC);
    hipLaunchKernelGGL(k_cvt_wtT, dim3(HC / 32, EDP / 32, 2), dim3(256), 0, stream,
                       t1_We, t2_We, t1_We, t1_We, w_e, ED, HC, EDP);
    hipLaunchKernelGGL(k_bcat2, dim3(16), dim3(256), 0, stream,
                       t1_bq, t1_bk, t1_bv, t1_bs, t2_bq, t2_bk, t2_bv, t2_bs, bcat);

    auto run_layer = [&](const ushort_t* xin_b, int Kin, const ushort_t* wcat,
                         const float* bc, const ushort_t* we,
                         ushort_t* xoutb, int poolmode) {
        int mt = (N_NODES + 127) / 128;
        int nt = NCAT / 128;
        int nq = mt * nt;                            // 2512
        int negc = (int)((ecap + 127) / 128) * 4;    // edge-GEMM grid per chunk

        // chunk 0 (nodes [0, n1)) fused with QKVS
        int n1 = (Nc < N_NODES) ? Nc : N_NODES;
        hipLaunchKernelGGL(k_mega, dim3(nq + negc), dim3(256), 0, stream,
                           xin_b, wcat, bc, qkvs, N_NODES, Kin, NCAT, nq,
                           ea_b, we, eb, rowptr, n1, negc);
        hipLaunchKernelGGL(k_edge_fc, dim3(n1), dim3(128), 0, stream,
                           qkvs, eb, psrc, rowptr, xoutb, 0);

        for (int ci = 1; ci < nchN; ++ci) {
            int nlo = ci * Nc;
            if (nlo >= N_NODES) break;
            int nhi = nlo + Nc; if (nhi > N_NODES) nhi = N_NODES;
            hipLaunchKernelGGL(k_egemm, dim3(negc), dim3(256), 0, stream,
                               ea_b, we, eb, rowptr, nlo, nhi);
            hipLaunchKernelGGL(k_edge_fc, dim3(nhi - nlo), dim3(128), 0, stream,
                               qkvs, eb, psrc, rowptr, xoutb, nlo);
        }

        // pooling (bf16 input, atomic-free partials)
        hipLaunchKernelGGL(k_pool2, dim3(NB, NSLICE), dim3(256), 0, stream,
                           xoutb, batch, psum_p, pmax_p, cnt);
        hipLaunchKernelGGL(k_poolfin, dim3((NB * 1024 + 255) / 256), dim3(256), 0, stream,
                           psum_p, pmax_p, cnt, hsum, poolmode);
    };

    // layer 1: x_b (N,128) -> x1_b ; layer 2: x1_b (N,512) -> x1_b
    run_layer(x_b, IN_CH, wcat1, bcat, w_e, x1_b, /*poolmode=*/0);
    run_layer(x1_b, HC, wcat2, bcat + NCAT, w_e + (size_t)HC * EDP, x1_b, /*poolmode=*/1);

    hipLaunchKernelGGL(k_head, dim3(NB), dim3(256), 0, stream,
                       hsum, fc1_W, fc1_b, fc2_W, fc2_b, (float*)d_out);
}

// Round 31
// 512.576 us; speedup vs baseline: 1.1453x; 1.0044x over previous
//
#include <hip/hip_runtime.h>
#include <cstdint>
#include <cstddef>

#define N_NODES 20000
#define N_EDGES 160000
#define IN_CH   128
#define NH      16
#define CD      32
#define HC      512   // NH*CD
#define ED      93
#define EDP     96    // ED padded to multiple of 32
#define NB      64
#define NCAT    2048  // q|k|v|skip GEMM output cols (all bf16)
#define NSLICE  8
#define ECSLK   2048  // edge-count slack per node-chunk (>=7 sigma of binomial split)

typedef __attribute__((ext_vector_type(8))) short short8;
typedef __attribute__((ext_vector_type(4))) float f32x4;
typedef __attribute__((ext_vector_type(4))) unsigned int u32x4;
typedef unsigned short ushort_t;

// ---------------------------------------------------------------- utilities

__device__ inline ushort_t f2bf(float f) {
    unsigned int u = __float_as_uint(f);
    u = (u + 0x7FFF + ((u >> 16) & 1)) >> 16;   // RNE
    return (ushort_t)u;
}
__device__ inline float bf2f(ushort_t u) {
    return __uint_as_float((unsigned)u << 16);
}
__device__ inline void unpack8(uint4 u, float* o) {
    o[0] = bf2f((ushort_t)(u.x & 0xffff)); o[1] = bf2f((ushort_t)(u.x >> 16));
    o[2] = bf2f((ushort_t)(u.y & 0xffff)); o[3] = bf2f((ushort_t)(u.y >> 16));
    o[4] = bf2f((ushort_t)(u.z & 0xffff)); o[5] = bf2f((ushort_t)(u.z >> 16));
    o[6] = bf2f((ushort_t)(u.w & 0xffff)); o[7] = bf2f((ushort_t)(u.w >> 16));
}
__device__ inline uint4 packf8(const float* f) {
    uint4 u;
    u.x = (unsigned)f2bf(f[0]) | ((unsigned)f2bf(f[1]) << 16);
    u.y = (unsigned)f2bf(f[2]) | ((unsigned)f2bf(f[3]) << 16);
    u.z = (unsigned)f2bf(f[4]) | ((unsigned)f2bf(f[5]) << 16);
    u.w = (unsigned)f2bf(f[6]) | ((unsigned)f2bf(f[7]) << 16);
    return u;
}

// non-temporal 16B load/store shims (builtin needs native vector types)
__device__ inline uint4 ntload16(const void* p) {
    u32x4 v = __builtin_nontemporal_load((const u32x4*)p);
    uint4 r; r.x = v.x; r.y = v.y; r.z = v.z; r.w = v.w; return r;
}
__device__ inline void ntstore16(void* p, uint4 v) {
    u32x4 t; t.x = v.x; t.y = v.y; t.z = v.z; t.w = v.w;
    __builtin_nontemporal_store(t, (u32x4*)p);
}

// async global->LDS, 16B per lane; lds dest = wave-uniform base + lane*16
__device__ inline void gload_lds16(const void* g, void* l) {
    __builtin_amdgcn_global_load_lds(
        (const __attribute__((address_space(1))) void*)g,
        (__attribute__((address_space(3))) void*)l, 16, 0, 0);
}

__global__ void k_zero_i(int* __restrict__ p, int n) {
    int i = blockIdx.x * blockDim.x + threadIdx.x;
    int stride = gridDim.x * blockDim.x;
    for (; i < n; i += stride) p[i] = 0;
}

// x f32 -> bf16, 8 elems/thread vectorized (n % 8 == 0)
__global__ void k_cvt_x(const float* __restrict__ in, ushort_t* __restrict__ out, int n8) {
    int i = blockIdx.x * blockDim.x + threadIdx.x;
    int stride = gridDim.x * blockDim.x;
    for (; i < n8; i += stride) {
        const float4* p = (const float4*)(in + (size_t)i * 8);
        float4 a = p[0], b = p[1];
        float f[8] = {a.x, a.y, a.z, a.w, b.x, b.y, b.z, b.w};
        *(uint4*)(out + (size_t)i * 8) = packf8(f);
    }
}

// edge_attr [E,93] f32 -> PERMUTED [E,96] bf16: out row p = in row perm[p].
__global__ void k_cvt_ea(const float* __restrict__ in, const int* __restrict__ perm,
                         ushort_t* __restrict__ out) {
    int i = blockIdx.x * blockDim.x + threadIdx.x;
    int stride = gridDim.x * blockDim.x;
    int total = N_EDGES * EDP;
    for (; i < total; i += stride) {
        int p = i / EDP, k = i - p * EDP;
        int e = perm[p];
        out[i] = (k < ED) ? f2bf(in[(size_t)e * ED + k]) : (ushort_t)0;
    }
}

// LDS-tiled transposed weight conversion
__global__ __launch_bounds__(256) void k_cvt_wtT(
    const float* __restrict__ W0, const float* __restrict__ W1,
    const float* __restrict__ W2, const float* __restrict__ W3,
    ushort_t* __restrict__ Wt, int K, int N, int Kp) {
    __shared__ float tile[32][33];
    int z = blockIdx.z;
    const float* W = (z == 0) ? W0 : (z == 1) ? W1 : (z == 2) ? W2 : W3;
    ushort_t* out = Wt + (size_t)z * N * Kp;
    int n0 = blockIdx.x << 5;
    int k0 = blockIdx.y << 5;
    int r = threadIdx.x >> 5;   // 0..7
    int c = threadIdx.x & 31;
#pragma unroll
    for (int rr = 0; rr < 4; ++rr) {
        int k = k0 + r + rr * 8;
        tile[r + rr * 8][c] = (k < K) ? W[(size_t)k * N + n0 + c] : 0.f;
    }
    __syncthreads();
#pragma unroll
    for (int rr = 0; rr < 4; ++rr) {
        int n = n0 + r + rr * 8;
        out[(size_t)n * Kp + k0 + c] = f2bf(tile[c][r + rr * 8]);
    }
}

// bcat[2][2048] = (bq|bk|bv|bs) per layer, one dispatch
__global__ void k_bcat2(
    const float* __restrict__ b0q, const float* __restrict__ b0k,
    const float* __restrict__ b0v, const float* __restrict__ b0s,
    const float* __restrict__ b1q, const float* __restrict__ b1k,
    const float* __restrict__ b1v, const float* __restrict__ b1s,
    float* __restrict__ out) {
    int i = blockIdx.x * blockDim.x + threadIdx.x;
    if (i >= 2 * NCAT) return;
    int l = i >> 11, j = i & (NCAT - 1);
    int s = j >> 9, jj = j & 511;
    const float* b = (l == 0)
        ? ((s == 0) ? b0q : (s == 1) ? b0k : (s == 2) ? b0v : b0s)
        : ((s == 0) ? b1q : (s == 1) ? b1k : (s == 2) ? b1v : b1s);
    out[i] = b[jj];
}

// ---------------------------------------------------------------- CSR build

__global__ void k_hist(const int* __restrict__ dst, int* __restrict__ deg) {
    int i = blockIdx.x * blockDim.x + threadIdx.x;
    if (i < N_EDGES) atomicAdd(&deg[dst[i]], 1);
}

__global__ __launch_bounds__(1024) void k_scan(const int* __restrict__ deg,
                                               int* __restrict__ rowptr,
                                               int* __restrict__ cursor) {
    __shared__ int part[1024];
    int t = threadIdx.x;
    int base = t * 20;
    int loc[20];
    int s = 0;
#pragma unroll
    for (int i = 0; i < 20; ++i) {
        int idx = base + i;
        int v = (idx < N_NODES) ? deg[idx] : 0;
        loc[i] = s; s += v;
    }
    part[t] = s;
    __syncthreads();
    for (int off = 1; off < 1024; off <<= 1) {
        int v = (t >= off) ? part[t - off] : 0;
        __syncthreads();
        part[t] += v;
        __syncthreads();
    }
    int pre = (t > 0) ? part[t - 1] : 0;
#pragma unroll
    for (int i = 0; i < 20; ++i) {
        int idx = base + i;
        if (idx < N_NODES) {
            int v = pre + loc[i];
            rowptr[idx] = v;
            cursor[idx] = v;
        }
    }
    if (t == 1023) rowptr[N_NODES] = part[1023];
}

__global__ void k_scatter(const int* __restrict__ src, const int* __restrict__ dst,
                          int* __restrict__ cursor, int* __restrict__ perm,
                          int* __restrict__ psrc) {
    int i = blockIdx.x * blockDim.x + threadIdx.x;
    if (i >= N_EDGES) return;
    int d = dst[i];
    int p = atomicAdd(&cursor[d], 1);
    perm[p] = i;
    psrc[p] = src[i];
}

// ---------------------------------------------------------------- MEGA kernel
// blocks [0,nq): QKVS GEMM; blocks [nq,nq+neg): edge-GEMM for nodes [0,n1).

__global__ __launch_bounds__(256) void k_mega(
    const ushort_t* __restrict__ A, const ushort_t* __restrict__ Bt,
    const float* __restrict__ bias, ushort_t* __restrict__ Yb,
    int M, int K, int N, int nq,
    const ushort_t* __restrict__ Ab, const ushort_t* __restrict__ Bte,
    ushort_t* __restrict__ Ybe, const int* __restrict__ rowptrd, int n1, int neg) {
    __shared__ char smem[49152];
    int tid  = threadIdx.x;
    int lane = tid & 63, wave = tid >> 6;
    int l15 = lane & 15, lg = lane >> 4;
    int wm = (wave >> 1) * 64, wn = (wave & 1) * 64;

    if ((int)blockIdx.x < nq) {
        // ---------------- QKVS body ----------------
        char* As = smem;
        char* Bs = smem + 16384;
        int nt = N >> 7;
        int bid = blockIdx.x;
        int wg;
        if ((nq & 7) == 0) { int cpx = nq >> 3; wg = (bid & 7) * cpx + (bid >> 3); }
        else wg = bid;
        int bm = (wg / nt) * 128, bn = (wg % nt) * 128;

        f32x4 acc[4][4] = {};

        int sr = lane >> 3;
        int su = lane & 7;
        int gu = su ^ sr;

        for (int k0 = 0; k0 < K; k0 += 64) {
#pragma unroll
            for (int i = 0; i < 4; ++i) {
                int rloc = wave * 32 + i * 8;
                int row = rloc + sr;
                if (bm + row < M)
                    gload_lds16(A + (size_t)(bm + row) * K + k0 + gu * 8, As + rloc * 128);
                gload_lds16(Bt + (size_t)(bn + row) * K + k0 + gu * 8, Bs + rloc * 128);
            }
            __syncthreads();

#pragma unroll
            for (int ks = 0; ks < 2; ++ks) {
                short8 af[4], bfr[4];
#pragma unroll
                for (int mr = 0; mr < 4; ++mr) {
                    int r = wm + mr * 16 + l15;
                    af[mr] = *(const short8*)(As + r * 128 + (((ks * 4 + lg) ^ (r & 7)) << 4));
                }
#pragma unroll
                for (int nc = 0; nc < 4; ++nc) {
                    int r = wn + nc * 16 + l15;
                    bfr[nc] = *(const short8*)(Bs + r * 128 + (((ks * 4 + lg) ^ (r & 7)) << 4));
                }
#pragma unroll
                for (int mr = 0; mr < 4; ++mr)
#pragma unroll
                    for (int nc = 0; nc < 4; ++nc)
                        acc[mr][nc] = __builtin_amdgcn_mfma_f32_16x16x32_bf16(
                            af[mr], bfr[nc], acc[mr][nc], 0, 0, 0);
            }
            __syncthreads();
        }

        char* Cs = smem;
#pragma unroll
        for (int mr = 0; mr < 4; ++mr) {
#pragma unroll
            for (int nc = 0; nc < 4; ++nc) {
                int coll = wn + nc * 16 + l15;
                float b = bias ? bias[bn + coll] : 0.f;
                int u0 = coll >> 3;
#pragma unroll
                for (int j = 0; j < 4; ++j) {
                    int row = wm + mr * 16 + lg * 4 + j;
                    int u = u0 ^ (row & 7);
                    *(ushort_t*)(Cs + row * 256 + (u << 4) + ((coll & 7) << 1)) =
                        f2bf(acc[mr][nc][j] + b);
                }
            }
        }
        __syncthreads();
        {
            int rsub = tid >> 4;
            int un   = tid & 15;
#pragma unroll
            for (int i = 0; i < 8; ++i) {
                int row = i * 16 + rsub;
                int gr = bm + row;
                if (gr < M) {
                    int u = un ^ (row & 7);
                    *(uint4*)(Yb + (size_t)gr * N + bn + un * 8) =
                        *(const uint4*)(Cs + row * 256 + (u << 4));
                }
            }
        }
    } else {
        // ---------------- edge-GEMM body (chunk 0: pbase = 0, ec from rowptr) ----------------
        int ec = rowptrd[n1];
        char* As = smem;
        char* Bs = smem + 24576;
        int bid = blockIdx.x - nq;
        int wg;
        if ((neg & 7) == 0) { int cpx = neg >> 3; wg = (bid & 7) * cpx + (bid >> 3); }
        else wg = bid;
        int bm = (wg >> 2) * 128;
        int n0 = (wg & 3) * 128;

        int srow = tid >> 1;
        int h    = tid & 1;
        int ssw  = ((srow >> 1) & 3) << 4;
        {
            int gm = bm + srow;
            uint4 va[6];
#pragma unroll
            for (int i = 0; i < 6; ++i) { va[i].x = va[i].y = va[i].z = va[i].w = 0; }
            if (gm < ec) {
                const uint4* ga = (const uint4*)(Ab + (size_t)gm * EDP + h * 48);
#pragma unroll
                for (int i = 0; i < 6; ++i) va[i] = ga[i];
            }
            char* dsta = As + srow * 192;
#pragma unroll
            for (int i = 0; i < 6; ++i) {
                int c = h * 96 + i * 16;
                *(uint4*)(dsta + ((c & ~63) | ((c & 63) ^ ssw))) = va[i];
            }
            uint4 vb[6];
            {
                const uint4* gb = (const uint4*)(Bte + (size_t)(n0 + srow) * EDP + h * 48);
#pragma unroll
                for (int i = 0; i < 6; ++i) vb[i] = gb[i];
            }
            char* dstb = Bs + srow * 192;
#pragma unroll
            for (int i = 0; i < 6; ++i) {
                int c = h * 96 + i * 16;
                *(uint4*)(dstb + ((c & ~63) | ((c & 63) ^ ssw))) = vb[i];
            }
        }
        __syncthreads();

        int fsw = ((l15 >> 1) & 3) << 4;

        f32x4 acc[4][4] = {};
#pragma unroll
        for (int ks = 0; ks < 3; ++ks) {
            short8 af[4], bfr[4];
#pragma unroll
            for (int mr = 0; mr < 4; ++mr) {
                int r = wm + mr * 16 + l15;
                int c = ks * 64 + ((lg * 16) ^ fsw);
                af[mr] = *(const short8*)(As + r * 192 + c);
            }
#pragma unroll
            for (int nc = 0; nc < 4; ++nc) {
                int r = wn + nc * 16 + l15;
                int c = ks * 64 + ((lg * 16) ^ fsw);
                bfr[nc] = *(const short8*)(Bs + r * 192 + c);
            }
#pragma unroll
            for (int mr = 0; mr < 4; ++mr)
#pragma unroll
                for (int nc = 0; nc < 4; ++nc)
                    acc[mr][nc] = __builtin_amdgcn_mfma_f32_16x16x32_bf16(
                        af[mr], bfr[nc], acc[mr][nc], 0, 0, 0);
        }
        __syncthreads();

        char* Cs = smem;   // 128 rows * 288B stride = 36864
#pragma unroll
        for (int mr = 0; mr < 4; ++mr) {
#pragma unroll
            for (int nc = 0; nc < 4; ++nc) {
                int col = wn + nc * 16 + l15;
#pragma unroll
                for (int j = 0; j < 4; ++j) {
                    int row = wm + mr * 16 + lg * 4 + j;
                    *(ushort_t*)(Cs + row * 288 + col * 2) = f2bf(acc[mr][nc][j]);
                }
            }
        }
        __syncthreads();

        {
            int rsub = tid >> 4;
            int un   = tid & 15;
#pragma unroll
            for (int i = 0; i < 8; ++i) {
                int row = i * 16 + rsub;
                if (bm + row < ec) {
                    ntstore16(Ybe + (size_t)(bm + row) * HC + n0 + un * 8,
                              *(const uint4*)(Cs + row * 288 + un * 16));
                }
            }
        }
    }
}

// ---------------------------------------------------------------- edge GEMM
// eb[r-pbase, :512] = ea_b[r, :96] @ We[512,96]^T for r in [rowptr[nlo], rowptr[nhi]).

__global__ __launch_bounds__(256) void k_egemm(
    const ushort_t* __restrict__ Ab, const ushort_t* __restrict__ Bt,
    ushort_t* __restrict__ Yb, const int* __restrict__ rowptrd,
    int nlo, int nhi) {
    __shared__ char smem[49152];
    char* As = smem;
    char* Bs = smem + 24576;

    int pbase = rowptrd[nlo];
    int ec    = rowptrd[nhi] - pbase;

    int tid  = threadIdx.x;
    int lane = tid & 63, wave = tid >> 6;
    int l15 = lane & 15, lg = lane >> 4;
    int nwg = gridDim.x;
    int bid = blockIdx.x;
    int wg;
    if ((nwg & 7) == 0) { int cpx = nwg >> 3; wg = (bid & 7) * cpx + (bid >> 3); }
    else wg = bid;
    int bm = (wg >> 2) * 128;
    int n0 = (wg & 3) * 128;
    int wm = (wave >> 1) * 64, wn = (wave & 1) * 64;

    int srow = tid >> 1;
    int h    = tid & 1;
    int ssw  = ((srow >> 1) & 3) << 4;
    {
        int gm = bm + srow;
        uint4 va[6];
#pragma unroll
        for (int i = 0; i < 6; ++i) { va[i].x = va[i].y = va[i].z = va[i].w = 0; }
        if (gm < ec) {
            const uint4* ga = (const uint4*)(Ab + (size_t)(pbase + gm) * EDP + h * 48);
#pragma unroll
            for (int i = 0; i < 6; ++i) va[i] = ga[i];
        }
        char* dsta = As + srow * 192;
#pragma unroll
        for (int i = 0; i < 6; ++i) {
            int c = h * 96 + i * 16;
            *(uint4*)(dsta + ((c & ~63) | ((c & 63) ^ ssw))) = va[i];
        }
        uint4 vb[6];
        {
            const uint4* gb = (const uint4*)(Bt + (size_t)(n0 + srow) * EDP + h * 48);
#pragma unroll
            for (int i = 0; i < 6; ++i) vb[i] = gb[i];
        }
        char* dstb = Bs + srow * 192;
#pragma unroll
        for (int i = 0; i < 6; ++i) {
            int c = h * 96 + i * 16;
            *(uint4*)(dstb + ((c & ~63) | ((c & 63) ^ ssw))) = vb[i];
        }
    }
    __syncthreads();

    int fsw = ((l15 >> 1) & 3) << 4;

    f32x4 acc[4][4] = {};
#pragma unroll
    for (int ks = 0; ks < 3; ++ks) {
        short8 af[4], bfr[4];
#pragma unroll
        for (int mr = 0; mr < 4; ++mr) {
            int r = wm + mr * 16 + l15;
            int c = ks * 64 + ((lg * 16) ^ fsw);
            af[mr] = *(const short8*)(As + r * 192 + c);
        }
#pragma unroll
        for (int nc = 0; nc < 4; ++nc) {
            int r = wn + nc * 16 + l15;
            int c = ks * 64 + ((lg * 16) ^ fsw);
            bfr[nc] = *(const short8*)(Bs + r * 192 + c);
        }
#pragma unroll
        for (int mr = 0; mr < 4; ++mr)
#pragma unroll
            for (int nc = 0; nc < 4; ++nc)
                acc[mr][nc] = __builtin_amdgcn_mfma_f32_16x16x32_bf16(
                    af[mr], bfr[nc], acc[mr][nc], 0, 0, 0);
    }
    __syncthreads();

    char* Cs = smem;   // 128 rows * 288B stride = 36864
#pragma unroll
    for (int mr = 0; mr < 4; ++mr) {
#pragma unroll
        for (int nc = 0; nc < 4; ++nc) {
            int col = wn + nc * 16 + l15;
#pragma unroll
            for (int j = 0; j < 4; ++j) {
                int row = wm + mr * 16 + lg * 4 + j;
                *(ushort_t*)(Cs + row * 288 + col * 2) = f2bf(acc[mr][nc][j]);
            }
        }
    }
    __syncthreads();

    {
        int rsub = tid >> 4;
        int un   = tid & 15;
#pragma unroll
        for (int i = 0; i < 8; ++i) {
            int row = i * 16 + rsub;
            if (bm + row < ec) {
                ntstore16(Yb + (size_t)(bm + row) * HC + n0 + un * 8,
                          *(const uint4*)(Cs + row * 288 + un * 16));
            }
        }
    }
}

// ---------------------------------------------------------------- fused edge phase
// NODE-RANGE variant, 32-LANES-PER-EDGE: block = 4 half-wave streams, each
// processes edges beg+hw, step 4; 16 elems (32B) per lane per segment.
// Depth-2 prefetch per stream -> 2 edges in flight per wave.

__global__ __launch_bounds__(128) void k_edge_fc(
    const ushort_t* __restrict__ qkvs, const ushort_t* __restrict__ eb,
    const int* __restrict__ psrc, const int* __restrict__ rowptrd,
    ushort_t* __restrict__ xoutb, int nlo) {
    int n = nlo + blockIdx.x;
    int e0 = rowptrd[nlo];
    int beg = rowptrd[n], end = rowptrd[n + 1];

    int t = threadIdx.x;
    int hw = t >> 5;         // stream 0..3
    int l32 = t & 31;
    int c0 = l32 * 16;       // 16 bf16 elems per lane
    int h = l32 >> 1;        // head 0..15 (2 lanes per head)

    // slot A (edge i), slot B (edge i+4) in flight
    uint4 ka0 = {}, ka1 = {}, va0 = {}, va1 = {}, ea0 = {}, ea1 = {};
    uint4 kb0 = {}, kb1 = {}, vb0 = {}, vb1 = {}, eb0 = {}, eb1 = {};
    int i = beg + hw;
    if (i < end) {
        int sn = psrc[i];
        const uint4* kp = (const uint4*)(qkvs + (size_t)sn * NCAT + 512 + c0);
        ka0 = kp[0]; ka1 = kp[1];
        const uint4* vp = (const uint4*)(qkvs + (size_t)sn * NCAT + 1024 + c0);
        va0 = vp[0]; va1 = vp[1];
        ea0 = ntload16(eb + (size_t)(i - e0) * HC + c0);
        ea1 = ntload16(eb + (size_t)(i - e0) * HC + c0 + 8);
    }
    if (i + 4 < end) {
        int sn = psrc[i + 4];
        const uint4* kp = (const uint4*)(qkvs + (size_t)sn * NCAT + 512 + c0);
        kb0 = kp[0]; kb1 = kp[1];
        const uint4* vp = (const uint4*)(qkvs + (size_t)sn * NCAT + 1024 + c0);
        vb0 = vp[0]; vb1 = vp[1];
        eb0 = ntload16(eb + (size_t)(i + 4 - e0) * HC + c0);
        eb1 = ntload16(eb + (size_t)(i + 4 - e0) * HC + c0 + 8);
    }

    float q[16];
    {
        const uint4* qp = (const uint4*)(qkvs + (size_t)n * NCAT + c0);
        unpack8(qp[0], q); unpack8(qp[1], q + 8);
    }

    float mm = -1e30f, dd = 0.f, a[16];
#pragma unroll
    for (int j = 0; j < 16; ++j) a[j] = 0.f;

    while (i < end) {
        uint4 kc0 = ka0, kc1 = ka1, vc0 = va0, vc1 = va1, ec0 = ea0, ec1 = ea1;
        ka0 = kb0; ka1 = kb1; va0 = vb0; va1 = vb1; ea0 = eb0; ea1 = eb1;
        int inx = i + 8;
        if (inx < end) {
            int sn2 = psrc[inx];
            const uint4* kp = (const uint4*)(qkvs + (size_t)sn2 * NCAT + 512 + c0);
            kb0 = kp[0]; kb1 = kp[1];
            const uint4* vp = (const uint4*)(qkvs + (size_t)sn2 * NCAT + 1024 + c0);
            vb0 = vp[0]; vb1 = vp[1];
            eb0 = ntload16(eb + (size_t)(inx - e0) * HC + c0);
            eb1 = ntload16(eb + (size_t)(inx - e0) * HC + c0 + 8);
        }
        float kk[16], vv[16], ee[16];
        unpack8(kc0, kk); unpack8(kc1, kk + 8);
        unpack8(vc0, vv); unpack8(vc1, vv + 8);
        unpack8(ec0, ee); unpack8(ec1, ee + 8);
        float part = 0.f;
#pragma unroll
        for (int j = 0; j < 16; ++j) part += q[j] * (kk[j] + ee[j]);
        part += __shfl_xor(part, 1);             // 2 lanes per head
        float s = part * 0.17677669529663687f;   // /sqrt(32)
        float mn = fmaxf(mm, s);
        float sc = __expf(mm - mn);
        float p  = __expf(s - mn);
        dd = dd * sc + p;
        mm = mn;
#pragma unroll
        for (int j = 0; j < 16; ++j) a[j] = a[j] * sc + p * (vv[j] + ee[j]);
        i += 4;
    }

    // merge the 4 stream states
    __shared__ float sm_acc[4][512];
    __shared__ float sm_m[4][16];
    __shared__ float sm_d[4][16];
#pragma unroll
    for (int j = 0; j < 16; ++j) sm_acc[hw][c0 + j] = a[j];
    if ((l32 & 1) == 0) { sm_m[hw][h] = mm; sm_d[hw][h] = dd; }
    __syncthreads();
    if (hw == 0) {
        float m0 = sm_m[0][h], m1 = sm_m[1][h], m2 = sm_m[2][h], m3 = sm_m[3][h];
        float M = fmaxf(fmaxf(m0, m1), fmaxf(m2, m3));
        float s0 = __expf(m0 - M), s1 = __expf(m1 - M);
        float s2 = __expf(m2 - M), s3 = __expf(m3 - M);
        float D = sm_d[0][h] * s0 + sm_d[1][h] * s1 + sm_d[2][h] * s2 + sm_d[3][h] * s3;
        float inv = (D > 0.f) ? 1.f / D : 0.f;
        float sk[16];
        {
            const uint4* sp = (const uint4*)(qkvs + (size_t)n * NCAT + 1536 + c0);
            unpack8(sp[0], sk); unpack8(sp[1], sk + 8);
        }
        float o[16];
#pragma unroll
        for (int j = 0; j < 16; ++j) {
            float numer = sm_acc[0][c0 + j] * s0 + sm_acc[1][c0 + j] * s1
                        + sm_acc[2][c0 + j] * s2 + sm_acc[3][c0 + j] * s3;
            float v = numer * inv + sk[j];
            o[j] = v >= 0.f ? v : 0.2f * v;
        }
        uint4* op = (uint4*)(xoutb + (size_t)n * HC + c0);
        op[0] = packf8(o); op[1] = packf8(o + 8);
    }
}

// ---------------------------------------------------------------- pooling (bf16 in)

__global__ __launch_bounds__(256) void k_pool2(
    const ushort_t* __restrict__ xb, const int* __restrict__ batch,
    float* __restrict__ psum_p, float* __restrict__ pmax_p, int* __restrict__ cnt) {
    int b = blockIdx.x;
    int s = blockIdx.y;
    int lo = 0, hi = N_NODES;
    while (lo < hi) { int mid = (lo + hi) >> 1; if (batch[mid] < b) lo = mid + 1; else hi = mid; }
    int beg = lo;
    hi = N_NODES;
    while (lo < hi) { int mid = (lo + hi) >> 1; if (batch[mid] < b + 1) lo = mid + 1; else hi = mid; }
    int end = lo;
    if (s == 0 && threadIdx.x == 0) cnt[b] = end - beg;
    int cn = end - beg;
    int per = (cn + NSLICE - 1) / NSLICE;
    int nb = beg + s * per;
    int ne = nb + per; if (ne > end) ne = end;
    int c0 = threadIdx.x * 2;
    float s0 = 0.f, s1 = 0.f, m0 = -1e30f, m1 = -1e30f;
    for (int n = nb; n < ne; ++n) {
        unsigned int v = *(const unsigned int*)(xb + (size_t)n * HC + c0);
        float v0 = bf2f((ushort_t)(v & 0xffff));
        float v1 = bf2f((ushort_t)(v >> 16));
        s0 += v0; s1 += v1;
        m0 = fmaxf(m0, v0); m1 = fmaxf(m1, v1);
    }
    size_t o = ((size_t)s * NB + b) * HC + c0;
    psum_p[o] = s0; psum_p[o + 1] = s1;
    pmax_p[o] = m0; pmax_p[o + 1] = m1;
}

__global__ void k_poolfin(const float* __restrict__ psum_p, const float* __restrict__ pmax_p,
                          const int* __restrict__ cnt, float* __restrict__ hsum, int mode) {
    int i = blockIdx.x * blockDim.x + threadIdx.x;
    if (i >= NB * 1024) return;
    int b = i >> 10, c = i & 1023;
    float val;
    if (c < HC) {
        float s = 0.f;
#pragma unroll
        for (int sl = 0; sl < NSLICE; ++sl)
            s += psum_p[((size_t)sl * NB + b) * HC + c];
        int ct = cnt[b];
        val = s / (float)(ct > 0 ? ct : 1);
    } else {
        int cc = c - HC;
        float m = -1e30f;
#pragma unroll
        for (int sl = 0; sl < NSLICE; ++sl)
            m = fmaxf(m, pmax_p[((size_t)sl * NB + b) * HC + cc]);
        val = m;
    }
    if (mode == 0) hsum[i] = val;
    else hsum[i] += val;
}

// ---------------------------------------------------------------- MLP head

__global__ __launch_bounds__(256) void k_head(
    const float* __restrict__ hsum, const float* __restrict__ fc1W,
    const float* __restrict__ fc1b, const float* __restrict__ fc2W,
    const float* __restrict__ fc2b, float* __restrict__ out) {
    int b = blockIdx.x;
    int j = threadIdx.x;
    __shared__ float hs[256];
    float acc = fc1b[j];
    const float* hin = hsum + (size_t)b * 1024;
    for (int k = 0; k < 1024; ++k) {
        acc += hin[k] * fc1W[(size_t)k * 256 + j];
    }
    hs[j] = fmaxf(acc, 0.f);
    __syncthreads();
    if (j < 32) {
        float o = fc2b[j];
        for (int k = 0; k < 256; ++k) o += hs[k] * fc2W[(size_t)k * 32 + j];
        out[b * 32 + j] = o;
    }
}

// ---------------------------------------------------------------- driver

extern "C" void kernel_launch(void* const* d_in, const int* in_sizes, int n_in,
                              void* d_out, int out_size, void* d_ws, size_t ws_size,
                              hipStream_t stream) {
    const float* x      = (const float*)d_in[0];
    const float* ea     = (const float*)d_in[1];
    const int*   ei     = (const int*)d_in[2];
    const int*   batch  = (const int*)d_in[3];
    const int* src = ei;
    const int* dst = ei + N_EDGES;

    const float* t1_Wq = (const float*)d_in[4];
    const float* t1_bq = (const float*)d_in[5];
    const float* t1_Wk = (const float*)d_in[6];
    const float* t1_bk = (const float*)d_in[7];
    const float* t1_Wv = (const float*)d_in[8];
    const float* t1_bv = (const float*)d_in[9];
    const float* t1_We = (const float*)d_in[10];
    const float* t1_Ws = (const float*)d_in[11];
    const float* t1_bs = (const float*)d_in[12];
    const float* t2_Wq = (const float*)d_in[13];
    const float* t2_bq = (const float*)d_in[14];
    const float* t2_Wk = (const float*)d_in[15];
    const float* t2_bk = (const float*)d_in[16];
    const float* t2_Wv = (const float*)d_in[17];
    const float* t2_bv = (const float*)d_in[18];
    const float* t2_We = (const float*)d_in[19];
    const float* t2_Ws = (const float*)d_in[20];
    const float* t2_bs = (const float*)d_in[21];
    const float* fc1_W = (const float*)d_in[22];
    const float* fc1_b = (const float*)d_in[23];
    const float* fc2_W = (const float*)d_in[24];
    const float* fc2_b = (const float*)d_in[25];

    char* ws = (char*)d_ws;
    size_t off = 0;
    auto alloc = [&](size_t bytes) -> void* {
        void* p = ws + off;
        off = (off + bytes + 255) & ~(size_t)255;
        return p;
    };

    // ---- fixed buffers ----
    ushort_t* qkvs = (ushort_t*)alloc((size_t)N_NODES * NCAT * 2);  // q|k|v|skip bf16
    float* psum_p = (float*)alloc((size_t)NSLICE * NB * HC * 4);
    float* pmax_p = (float*)alloc((size_t)NSLICE * NB * HC * 4);
    float* hsum = (float*)alloc((size_t)NB * 1024 * 4);
    int*   cnt  = (int*)alloc((size_t)NB * 4);
    int* deg    = (int*)alloc((size_t)N_NODES * 4);
    int* rowptr = (int*)alloc((size_t)(N_NODES + 1) * 4);
    int* cursor = (int*)alloc((size_t)N_NODES * 4);
    int* perm   = (int*)alloc((size_t)N_EDGES * 4);
    int* psrc   = (int*)alloc((size_t)N_EDGES * 4);
    ushort_t* x_b  = (ushort_t*)alloc((size_t)N_NODES * IN_CH * 2);
    ushort_t* x1_b = (ushort_t*)alloc((size_t)N_NODES * HC * 2);
    ushort_t* ea_b = (ushort_t*)alloc((size_t)N_EDGES * EDP * 2);   // dst-sorted
    ushort_t* wcat1 = (ushort_t*)alloc((size_t)NCAT * IN_CH * 2);
    ushort_t* wcat2 = (ushort_t*)alloc((size_t)NCAT * HC * 2);
    ushort_t* w_e   = (ushort_t*)alloc((size_t)2 * HC * EDP * 2);  // [2][HC][EDP]
    float* bcat = (float*)alloc((size_t)2 * NCAT * 4);             // [2][NCAT]

    // ---- eb: node-range chunk window, sized from remaining workspace ----
    size_t remain = (ws_size > off) ? (ws_size - off) : 0;
    ushort_t* eb = (ushort_t*)(ws + off);
    size_t per_edge = (size_t)HC * 2;                // 1 KiB per edge row
    long cap_rows = (long)(remain / per_edge);
    int nchN = 1;
    long ecap = N_EDGES;
    if (cap_rows < (long)N_EDGES) {
        nchN = -1;
        for (int c = 2; c <= 64; ++c) {
            long e = (long)(N_EDGES + c - 1) / c + ECSLK;
            if (e <= cap_rows) { nchN = c; ecap = e; break; }
        }
        if (nchN < 0) { nchN = 64; ecap = cap_rows > 1024 ? cap_rows : 1024; }
    }
    int Nc = (N_NODES + nchN - 1) / nchN;            // nodes per chunk
    (void)in_sizes; (void)n_in; (void)out_size;

    // ---- CSR build (before ea conversion: k_cvt_ea uses perm)
    hipLaunchKernelGGL(k_zero_i, dim3(79), dim3(256), 0, stream, deg, N_NODES);
    hipLaunchKernelGGL(k_hist, dim3((N_EDGES + 255) / 256), dim3(256), 0, stream, dst, deg);
    hipLaunchKernelGGL(k_scan, dim3(1), dim3(1024), 0, stream, deg, rowptr, cursor);
    hipLaunchKernelGGL(k_scatter, dim3((N_EDGES + 255) / 256), dim3(256), 0, stream,
                       src, dst, cursor, perm, psrc);

    // ---- conversions
    hipLaunchKernelGGL(k_cvt_x, dim3(512), dim3(256), 0, stream, x, x_b,
                       N_NODES * IN_CH / 8);
    hipLaunchKernelGGL(k_cvt_ea, dim3(4096), dim3(256), 0, stream, ea, perm, ea_b);
    hipLaunchKernelGGL(k_cvt_wtT, dim3(HC / 32, IN_CH / 32, 4), dim3(256), 0, stream,
                       t1_Wq, t1_Wk, t1_Wv, t1_Ws, wcat1, IN_CH, HC, IN_CH);
    hipLaunchKernelGGL(k_cvt_wtT, dim3(HC / 32, HC / 32, 4), dim3(256), 0, stream,
                       t2_Wq, t2_Wk, t2_Wv, t2_Ws, wcat2, HC, HC, HC);
    hipLaunchKernelGGL(k_cvt_wtT, dim3(HC / 32, EDP / 32, 2), dim3(256), 0, stream,
                       t1_We, t2_We, t1_We, t1_We, w_e, ED, HC, EDP);
    hipLaunchKernelGGL(k_bcat2, dim3(16), dim3(256), 0, stream,
                       t1_bq, t1_bk, t1_bv, t1_bs, t2_bq, t2_bk, t2_bv, t2_bs, bcat);

    auto run_layer = [&](const ushort_t* xin_b, int Kin, const ushort_t* wcat,
                         const float* bc, const ushort_t* we,
                         ushort_t* xoutb, int poolmode) {
        int mt = (N_NODES + 127) / 128;
        int nt = NCAT / 128;
        int nq = mt * nt;                            // 2512
        int negc = (int)((ecap + 127) / 128) * 4;    // edge-GEMM grid per chunk

        // chunk 0 (nodes [0, n1)) fused with QKVS
        int n1 = (Nc < N_NODES) ? Nc : N_NODES;
        hipLaunchKernelGGL(k_mega, dim3(nq + negc), dim3(256), 0, stream,
                           xin_b, wcat, bc, qkvs, N_NODES, Kin, NCAT, nq,
                           ea_b, we, eb, rowptr, n1, negc);
        hipLaunchKernelGGL(k_edge_fc, dim3(n1), dim3(128), 0, stream,
                           qkvs, eb, psrc, rowptr, xoutb, 0);

        for (int ci = 1; ci < nchN; ++ci) {
            int nlo = ci * Nc;
            if (nlo >= N_NODES) break;
            int nhi = nlo + Nc; if (nhi > N_NODES) nhi = N_NODES;
            hipLaunchKernelGGL(k_egemm, dim3(negc), dim3(256), 0, stream,
                               ea_b, we, eb, rowptr, nlo, nhi);
            hipLaunchKernelGGL(k_edge_fc, dim3(nhi - nlo), dim3(128), 0, stream,
                               qkvs, eb, psrc, rowptr, xoutb, nlo);
        }

        // pooling (bf16 input, atomic-free partials)
        hipLaunchKernelGGL(k_pool2, dim3(NB, NSLICE), dim3(256), 0, stream,
                           xoutb, batch, psum_p, pmax_p, cnt);
        hipLaunchKernelGGL(k_poolfin, dim3((NB * 1024 + 255) / 256), dim3(256), 0, stream,
                           psum_p, pmax_p, cnt, hsum, poolmode);
    };

    // layer 1: x_b (N,128) -> x1_b ; layer 2: x1_b (N,512) -> x1_b
    run_layer(x_b, IN_CH, wcat1, bcat, w_e, x1_b, /*poolmode=*/0);
    run_layer(x1_b, HC, wcat2, bcat + NCAT, w_e + (size_t)HC * EDP, x1_b, /*poolmode=*/1);

    hipLaunchKernelGGL(k_head, dim3(NB), dim3(256), 0, stream,
                       hsum, fc1_W, fc1_b, fc2_W, fc2_b, (float*)d_out);
}